// Round 16
// baseline (392.984 us; speedup 1.0000x reference)
//
#include <hip/hip_runtime.h>

typedef __bf16 bf16;
typedef __bf16 bf16x8 __attribute__((ext_vector_type(8)));
typedef __bf16 bf16x4v __attribute__((ext_vector_type(4)));
typedef short s16x4 __attribute__((ext_vector_type(4)));
typedef float f32x4 __attribute__((ext_vector_type(4)));
typedef unsigned int u32;
typedef unsigned long long u64;

#define NN 384
#define CC 128
#define LOG2E 1.44269504088896f

#define MFMA16(a,b,c) __builtin_amdgcn_mfma_f32_16x16x32_bf16(a,b,c,0,0,0)

// 16x16x16 bf16 MFMA
#if __has_builtin(__builtin_amdgcn_mfma_f32_16x16x16_bf16)
typedef bf16x4v pvab_t;
static __device__ __forceinline__ f32x4 PVMFMA(pvab_t A, bf16x4v B, f32x4 C){
  return __builtin_amdgcn_mfma_f32_16x16x16_bf16(A, B, C, 0,0,0);
}
static __device__ __forceinline__ pvab_t mk_pvab(u32 w0, u32 w1){
  return __builtin_bit_cast(pvab_t, (u64)w0 | ((u64)w1<<32));
}
#else
typedef s16x4 pvab_t;
static __device__ __forceinline__ f32x4 PVMFMA(pvab_t A, bf16x4v B, f32x4 C){
  return __builtin_amdgcn_mfma_f32_16x16x16bf16_1k(A, __builtin_bit_cast(s16x4, B), C, 0,0,0);
}
static __device__ __forceinline__ pvab_t mk_pvab(u32 w0, u32 w1){
  return __builtin_bit_cast(pvab_t, (u64)w0 | ((u64)w1<<32));
}
#endif

static __device__ __forceinline__ u32 bpack(float a, float b){
  unsigned short x = __builtin_bit_cast(unsigned short, (bf16)a);
  unsigned short y = __builtin_bit_cast(unsigned short, (bf16)b);
  return (u32)x | ((u32)y<<16);
}

// ---------------- workspace layout (bytes) ----------------
#define WS_NB   37748736          // nb fp32 [h][q][k] (pre-scaled by log2e)
#define WS_QKVG 40108032          // qkvg B-frag pack
#define WS_OP   40239104          // o_w pack
#define WS_KB   40271872          // K A-frags bf16 [b][h][24KiB]; reused as wavg after read
#define WS_VB   78020608          // V B16-frags bf16 [b][h][24KiB] (masked rows zeroed)
#define WS_NEED 115769344

__device__ __forceinline__ void async_copy16(void* lds_dst, const void* gsrc){
  __builtin_amdgcn_global_load_lds((const __attribute__((address_space(1))) u32*)gsrc,
                                   (__attribute__((address_space(3))) u32*)lds_dst, 16, 0, 0);
}

// ---------------- K0: pre-pack weights into MFMA B-fragment order ----------------
// exp2-folding: q_w scaled by D^-0.5 * log2e; gating_w scaled by log2e.
__global__ __launch_bounds__(256) void pack_kernel(
    const float* __restrict__ qw, const float* __restrict__ kw,
    const float* __restrict__ vw, const float* __restrict__ gw,
    const float* __restrict__ ow, bf16* __restrict__ qkvg, bf16* __restrict__ op)
{
  int tid = blockIdx.x*256 + threadIdx.x;
  int lane = tid & 63, frag = tid >> 6;
  if (frag < 128) {                       // ((wm*4+h)*4+t)*2+f
    int f = frag & 1, t = (frag>>1)&3, h = (frag>>3)&3, wm = frag>>5;
    const float* W = wm==0?qw: (wm==1?kw: (wm==2?vw: gw));
    float sc = (wm==0) ? 0.17677669529663687f*LOG2E : (wm==3 ? LOG2E : 1.0f);
    int d = f*16 + (lane&15);
    #pragma unroll
    for (int j=0;j<8;j++){
      int c = t*32 + (lane>>4)*8 + j;
      qkvg[tid*8 + j] = (bf16)(W[c*128 + h*32 + d]*sc);
    }
  } else if (frag < 160) {                // o_w
    int fr = frag - 128, f = fr & 7, t = fr>>3;
    int c = f*16 + (lane&15);
    #pragma unroll
    for (int j=0;j<8;j++){
      int d = (lane>>4)*8 + j;
      op[(fr*64 + lane)*8 + j] = (bf16)ow[(t*32 + d)*128 + c];
    }
  }
}

// ---------------- K1: LayerNorm (fp32) -> x bf16, + nb_bias [h][q][k] * log2e ----------------
__global__ __launch_bounds__(256) void ln_kernel(
    const float* __restrict__ pa, const float* __restrict__ lns,
    const float* __restrict__ lnb, const float* __restrict__ fw,
    bf16* __restrict__ xout, float* __restrict__ nbout)
{
  int wid = (blockIdx.x*256 + threadIdx.x) >> 6;
  int lane = threadIdx.x & 63;
  int nw = (gridDim.x*256) >> 6;
  float2 sc = *(const float2*)(lns + lane*2);
  float2 bi = *(const float2*)(lnb + lane*2);
  float4 f0 = *(const float4*)(fw + lane*8);
  float4 f1 = *(const float4*)(fw + lane*8 + 4);
  for (int row = wid; row < NN*NN; row += nw){
    float2 v = *(const float2*)(pa + row*128 + lane*2);
    float s = v.x + v.y;
    float sq = v.x*v.x + v.y*v.y;
    #pragma unroll
    for (int m=1;m<64;m<<=1){ s += __shfl_xor(s,m); sq += __shfl_xor(sq,m); }
    float mu = s*(1.f/128.f);
    float rstd = rsqrtf(sq*(1.f/128.f) - mu*mu + 1e-5f);
    float x0 = (v.x-mu)*rstd*sc.x + bi.x;
    float x1 = (v.y-mu)*rstd*sc.y + bi.y;
    unsigned short h0 = __builtin_bit_cast(unsigned short, (bf16)x0);
    unsigned short h1 = __builtin_bit_cast(unsigned short, (bf16)x1);
    *(unsigned int*)((char*)xout + row*256 + lane*4) = ((unsigned int)h1<<16)|h0;
    float4 t;
    t.x = x0*f0.x + x1*f1.x;
    t.y = x0*f0.y + x1*f1.y;
    t.z = x0*f0.z + x1*f1.z;
    t.w = x0*f0.w + x1*f1.w;
    #pragma unroll
    for (int m=1;m<64;m<<=1){
      t.x += __shfl_xor(t.x,m); t.y += __shfl_xor(t.y,m);
      t.z += __shfl_xor(t.z,m); t.w += __shfl_xor(t.w,m);
    }
    float vsel = (lane==0)?t.x : (lane==1)?t.y : (lane==2)?t.z : t.w;
    if (lane < 4) nbout[(size_t)lane*(NN*NN) + row] = vsel*LOG2E;
  }
}

// ---------------- K2: K/V projection GEMM -> fragment-packed buffers ----------------
__global__ __launch_bounds__(256) void proj_kv_kernel(
    const bf16* __restrict__ xg, const bf16* __restrict__ qkvg,
    const int* __restrict__ mask, bf16* __restrict__ kbuf, bf16* __restrict__ vbuf)
{
  __shared__ char psm[16384];
  const int w = threadIdx.x>>6, lane = threadIdx.x&63, g = (lane>>4)&3, l15 = lane&15;
  const int W = blockIdx.x*4 + w;
  const int rt = W>>1, wm = 1 + (W&1);
  const f32x4 Z = {0.f,0.f,0.f,0.f};
  f32x4 acc[8];
  #pragma unroll
  for (int f8=0;f8<8;f8++) acc[f8] = Z;
  const bf16* xrow = xg + (size_t)(rt*16 + l15)*CC;
  #pragma unroll
  for (int t=0;t<4;t++){
    bf16x8 a = *(const bf16x8*)(xrow + t*32 + g*8);
    #pragma unroll
    for (int f8=0; f8<8; f8++){
      int h = f8>>1, fh = f8&1;
      bf16x8 bb = *(const bf16x8*)(qkvg + (((wm*4+h)*4+t)*2+fh)*512 + lane*8);
      acc[f8] = MFMA16(a, bb, acc[f8]);
    }
  }
  const int bq = rt/24, tau = rt%24;
  if (wm==1){
    char* scr = psm + w*4096;
    #pragma unroll
    for (int f8=0; f8<8; f8++){
      #pragma unroll
      for (int j=0;j<4;j++){
        unsigned r = g*4+j;
        *(bf16*)(scr + ((r*256 + (f8*16+l15)*2) ^ (((r>>1)&7)<<4))) = (bf16)acc[f8][j];
      }
    }
    #pragma unroll
    for (int h=0;h<4;h++){
      bf16x8 kf = *(const bf16x8*)(scr + ((l15*256 + h*64 + g*16) ^ (((l15>>1)&7)<<4)));
      *(bf16x8*)(kbuf + (((size_t)(bq*4+h)*24 + tau)*64 + lane)*8) = kf;
    }
  } else {
    // zero masked key rows (C/D row = key = tau*16 + 4g + j); harmless belt+braces
    int4 mi = *(const int4*)(mask + bq*NN + tau*16 + g*4);
    float mb[4] = { mi.x?1.f:0.f, mi.y?1.f:0.f, mi.z?1.f:0.f, mi.w?1.f:0.f };
    #pragma unroll
    for (int f8=0; f8<8; f8++){
      #pragma unroll
      for (int j=0;j<4;j++) acc[f8][j] *= mb[j];
    }
    #pragma unroll
    for (int h=0;h<4;h++){
      f32x4 a0 = acc[h*2+0], a1 = acc[h*2+1];
      uint4 st4;
      st4.x = bpack(a0[0], a0[1]);
      st4.y = bpack(a0[2], a0[3]);
      st4.z = bpack(a1[0], a1[1]);
      st4.w = bpack(a1[2], a1[3]);
      *(uint4*)((char*)vbuf + ((size_t)(bq*4+h)*24 + tau)*1024 + lane*16) = st4;
    }
  }
}

// ---------------- K3: attention v16 ----------------
// Changes vs v15 (counter-driven):
//  (1) waves_per_eu(3,8): the min=2 attrs were the TRUE occupancy cap (compiler
//      allocates to the min-waves budget: 256 unified regs -> 2 waves/EU runtime
//      across v12-v15 regardless of LDS). 170-reg budget -> 3 waves/EU; the
//      fixed-max softmax live set (~130) now fits.
//  (2) drop o2 denominator MFMA (v14's regression: lengthened the serial
//      C-chained MFMA stream 48->72); restore v12's in-lane sum + 2 shuffles,
//      mask as bf16 bias add. nb stays as S-MFMA C-init (chain-neutral).
//  (3) PV accumulators split by nf-parity (4 chains) -> MFMA dep chain halved.
#define L16_SCR  24576            // 4 x 1 KiB per-wave scratch
#define L16_MASK 28672            // bf16 bias [384] (= log2e * 1e9 * (m-1))
#define L16_TOT  29440

__global__ __attribute__((amdgpu_flat_work_group_size(256,256), amdgpu_waves_per_eu(3,8)))
void attn_kernel16(
    const bf16* __restrict__ xg, const int* __restrict__ mask,
    const float* __restrict__ nb, const bf16* __restrict__ qkvg,
    bf16* __restrict__ kbuf, const bf16* __restrict__ vbuf,
    const float* __restrict__ gb)
{
  __shared__ char sm[L16_TOT];
  const int tid = threadIdx.x;
  const int lane = tid & 63, w = tid >> 6;
  const int g = (lane >> 4)&3, l15 = lane & 15;
  const f32x4 Z = {0.f,0.f,0.f,0.f};

  // h-major: concurrent blocks share one nb[h] plane (L2-resident)
  const u32 bid = blockIdx.x;
  const int h = bid / 384;
  const int b = bid - h*384;

  const char* kbh = (const char*)kbuf + ((size_t)b*4 + h)*24576;
  const char* vbh = (const char*)vbuf + ((size_t)b*4 + h)*24576;

  // ---- stage K (24KiB) + mask bias bf16 (768B) ----
  #pragma unroll
  for (int i=0;i<6;i++){
    unsigned u = (i*4 + w)*1024;
    async_copy16(sm + u, kbh + u + lane*16);
  }
  for (int k = tid; k < NN; k += 256)
    *(bf16*)(sm + L16_MASK + k*2) = (bf16)(1.44269504e9f*((float)mask[b*NN + k] - 1.0f));
  __syncthreads();   // vmcnt+lgkm drain; all staging visible

  const unsigned scb = L16_SCR + w*1024;
  const float* nbh = nb + (size_t)h*(NN*NN);

  for (int i=0;i<6;i++){
    const int qt = w*6 + i;
    const int qb = qt*16;

    // x A-frags for this q-tile
    bf16x8 a4[4];
    #pragma unroll
    for (int t=0;t<4;t++)
      a4[t] = *(const bf16x8*)(xg + (size_t)(b*NN + qb + l15)*CC + t*32 + g*8);

    // ---- Q projection ----
    f32x4 q0=Z, q1=Z;
    #pragma unroll
    for (int t=0;t<4;t++){
      bf16x8 bq0 = *(const bf16x8*)(qkvg + (((0*4+h)*4+t)*2+0)*512 + lane*8);
      bf16x8 bq1 = *(const bf16x8*)(qkvg + (((0*4+h)*4+t)*2+1)*512 + lane*8);
      q0 = MFMA16(a4[t], bq0, q0);
      q1 = MFMA16(a4[t], bq1, q1);
    }
    // bounce Q accum -> B-frag (lane holds Q[q=l15][d=g*8+j])
    #pragma unroll
    for (int f=0;f<2;f++){
      f32x4 qq = f ? q1 : q0;
      #pragma unroll
      for (int j=0;j<4;j++){
        unsigned r = g*4 + j, cb = (f*16 + l15)*2;
        *(bf16*)(sm + scb + ((r*64 + cb) ^ (((r>>1)&7)<<4))) = (bf16)qq[j];
      }
    }
    bf16x8 aq = *(const bf16x8*)(sm + scb + ((l15*64 + g*16) ^ (((l15>>1)&7)<<4)));

    // ---- fixed-max softmax (exp2 domain) + register PV, six 64-key chunks ----
    float sum_ = 0.f;
    f32x4 o00=Z, o01=Z, o10=Z, o11=Z;    // PV chains split by nf parity
    const float* nbq = nbh + (size_t)(qb + l15)*NN;

    #pragma unroll
    for (int c=0;c<6;c++){
      // V prefetch for this chunk (independent of the S/exp chain -> overlaps)
      bf16x8 vv[4];
      #pragma unroll
      for (int nf=0;nf<4;nf++)
        vv[nf] = *(const bf16x8*)(vbh + (c*4+nf)*1024 + lane*16);

      f32x4 st[4];
      #pragma unroll
      for (int nf=0;nf<4;nf++){
        float4 nbv = *(const float4*)(nbq + c*64 + nf*16 + g*4);
        bf16x8 ka = *(const bf16x8*)(sm + (c*4+nf)*1024 + lane*16);
        st[nf] = MFMA16(ka, aq, __builtin_bit_cast(f32x4, nbv));   // C-init = nb
      }
      #pragma unroll
      for (int nf=0;nf<4;nf++){
        bf16x4v mk4 = *(const bf16x4v*)(sm + L16_MASK + (c*64 + nf*16 + g*4)*2);
        #pragma unroll
        for (int j=0;j<4;j++){
          float pv = exp2f(st[nf][j] + (float)mk4[j] - 28.8539008178f); // == exp(S-20)
          st[nf][j] = pv;
          sum_ += pv;
        }
      }
      #pragma unroll
      for (int nf=0;nf<4;nf++){
        pvab_t pa = mk_pvab(bpack(st[nf][0], st[nf][1]), bpack(st[nf][2], st[nf][3]));
        bf16x4v vlo = {vv[nf][0],vv[nf][1],vv[nf][2],vv[nf][3]};
        bf16x4v vhi = {vv[nf][4],vv[nf][5],vv[nf][6],vv[nf][7]};
        if (nf & 1){ o01 = PVMFMA(pa, vlo, o01); o11 = PVMFMA(pa, vhi, o11); }
        else       { o00 = PVMFMA(pa, vlo, o00); o10 = PVMFMA(pa, vhi, o10); }
      }
    } // c

    f32x4 o0, o1;
    #pragma unroll
    for (int j=0;j<4;j++){ o0[j] = o00[j]+o01[j]; o1[j] = o10[j]+o11[j]; }

    // deferred cross-lane sum reduce + broadcast to C/D rows
    sum_ += __shfl_xor(sum_, 16);
    sum_ += __shfl_xor(sum_, 32);
    float rsl = 1.f/sum_;
    float rcd[4];
    #pragma unroll
    for (int j=0;j<4;j++)
      rcd[j] = __shfl(rsl, (lane & 0x30) + g*4 + j);

    // ---- gate projection (post-PV) ----
    f32x4 g0=Z, g1=Z;
    #pragma unroll
    for (int t=0;t<4;t++){
      bf16x8 bg0 = *(const bf16x8*)(qkvg + (((3*4+h)*4+t)*2+0)*512 + lane*8);
      bf16x8 bg1 = *(const bf16x8*)(qkvg + (((3*4+h)*4+t)*2+1)*512 + lane*8);
      g0 = MFMA16(a4[t], bg0, g0);
      g1 = MFMA16(a4[t], bg1, g1);
    }

    // ---- wg = (O/s)*sigmoid; bounce to A-frag; store to wavg (kbuf region) ----
    #pragma unroll
    for (int f=0;f<2;f++){
      f32x4 ov = f ? o1 : o0, gv = f ? g1 : g0;
      int d = f*16 + l15;
      float gbv = gb[h*32 + d]*LOG2E;
      #pragma unroll
      for (int j=0;j<4;j++){
        float gt = 1.f/(1.f + exp2f(-(gv[j] + gbv)));
        float wg = ov[j]*rcd[j]*gt;
        unsigned r = g*4 + j, cb2 = (unsigned)d*2;
        *(bf16*)(sm + scb + ((r*64 + cb2) ^ (((r>>1)&7)<<4))) = (bf16)wg;
      }
    }
    bf16x8 awg = *(const bf16x8*)(sm + scb + ((l15*64 + g*16) ^ (((l15>>1)&7)<<4)));
    *(bf16x8*)((char*)kbuf + ((size_t)b*4 + h)*24576 + qt*1024 + lane*16) = awg;
  } // i (q-tiles)
}

// ---------------- K4: out-projection GEMM: out = wavg · o_w + ob ----------------
__global__ __launch_bounds__(256) void outproj_kernel(
    const bf16* __restrict__ wavg, const bf16* __restrict__ opk,
    const float* __restrict__ ob, float* __restrict__ out)
{
  const int w = threadIdx.x>>6, lane = threadIdx.x&63;
  const int g = (lane>>4)&3, l15 = lane&15;
  const f32x4 Z = {0.f,0.f,0.f,0.f};
  const int W = blockIdx.x*4 + w;
  const int b = W/24, qt = W%24, qb = qt*16;

  bf16x8 aw[4];
  #pragma unroll
  for (int h=0;h<4;h++)
    aw[h] = *(const bf16x8*)((const char*)wavg + ((size_t)b*4 + h)*24576 + qt*1024 + lane*16);

  f32x4 outa[8];
  #pragma unroll
  for (int nf=0;nf<8;nf++) outa[nf] = Z;
  #pragma unroll
  for (int h=0;h<4;h++){
    #pragma unroll
    for (int nf=0;nf<8;nf++){
      bf16x8 bo = *(const bf16x8*)(opk + ((h*8+nf)*64 + lane)*8);
      outa[nf] = MFMA16(aw[h], bo, outa[nf]);
    }
  }
  #pragma unroll
  for (int nf=0;nf<8;nf++){
    int c = nf*16 + l15;
    float obv = ob[c];
    #pragma unroll
    for (int j=0;j<4;j++){
      int qi = qb + g*4 + j;
      out[((size_t)b*NN + qi)*CC + c] = outa[nf][j] + obv;
    }
  }
}

extern "C" void kernel_launch(void* const* d_in, const int* in_sizes, int n_in,
                              void* d_out, int out_size, void* d_ws, size_t ws_size,
                              hipStream_t stream)
{
  (void)in_sizes; (void)n_in; (void)out_size; (void)ws_size;
  const float* pa  = (const float*)d_in[0];
  const int*   msk = (const int*)d_in[1];
  const float* lns = (const float*)d_in[2];
  const float* lnb = (const float*)d_in[3];
  const float* fw  = (const float*)d_in[4];
  const float* qw  = (const float*)d_in[5];
  const float* kw  = (const float*)d_in[6];
  const float* vw  = (const float*)d_in[7];
  const float* gw  = (const float*)d_in[8];
  const float* gbv = (const float*)d_in[9];
  const float* ow  = (const float*)d_in[10];
  const float* ob  = (const float*)d_in[11];
  float* out = (float*)d_out;

  char* ws = (char*)d_ws;
  bf16*  xbuf  = (bf16*)(ws);
  float* nbbuf = (float*)(ws + WS_NB);
  bf16*  qkvg  = (bf16*)(ws + WS_QKVG);
  bf16*  opk   = (bf16*)(ws + WS_OP);
  bf16*  kbuf  = (bf16*)(ws + WS_KB);
  bf16*  vbuf  = (bf16*)(ws + WS_VB);

  pack_kernel<<<40, 256, 0, stream>>>(qw, kw, vw, gw, ow, qkvg, opk);
  ln_kernel<<<1152, 256, 0, stream>>>(pa, lns, lnb, fw, xbuf, nbbuf);
  proj_kv_kernel<<<4608, 256, 0, stream>>>(xbuf, qkvg, msk, kbuf, vbuf);
  attn_kernel16<<<1536, 256, 0, stream>>>(xbuf, msk, nbbuf, qkvg, kbuf, vbuf, gbv);
  outproj_kernel<<<2304, 256, 0, stream>>>(kbuf, opk, ob, out);
}

// Round 17
// 334.117 us; speedup vs baseline: 1.1762x; 1.1762x over previous
//
#include <hip/hip_runtime.h>

typedef __bf16 bf16;
typedef __bf16 bf16x8 __attribute__((ext_vector_type(8)));
typedef __bf16 bf16x4v __attribute__((ext_vector_type(4)));
typedef short s16x4 __attribute__((ext_vector_type(4)));
typedef float f32x4 __attribute__((ext_vector_type(4)));
typedef unsigned int u32;
typedef unsigned long long u64;

#define NN 384
#define CC 128
#define LOG2E 1.44269504088896f

#define MFMA16(a,b,c) __builtin_amdgcn_mfma_f32_16x16x32_bf16(a,b,c,0,0,0)

// 16x16x16 bf16 MFMA
#if __has_builtin(__builtin_amdgcn_mfma_f32_16x16x16_bf16)
typedef bf16x4v pvab_t;
static __device__ __forceinline__ f32x4 PVMFMA(pvab_t A, bf16x4v B, f32x4 C){
  return __builtin_amdgcn_mfma_f32_16x16x16_bf16(A, B, C, 0,0,0);
}
#else
typedef s16x4 pvab_t;
static __device__ __forceinline__ f32x4 PVMFMA(pvab_t A, bf16x4v B, f32x4 C){
  return __builtin_amdgcn_mfma_f32_16x16x16bf16_1k(A, __builtin_bit_cast(s16x4, B), C, 0,0,0);
}
#endif
static __device__ __forceinline__ pvab_t mk_pvab(u32 w0, u32 w1){
  return __builtin_bit_cast(pvab_t, (u64)w0 | ((u64)w1<<32));
}
static __device__ __forceinline__ pvab_t as_pvab(bf16x4v v){
  return __builtin_bit_cast(pvab_t, v);
}

static __device__ __forceinline__ u32 bpack(float a, float b){
  unsigned short x = __builtin_bit_cast(unsigned short, (bf16)a);
  unsigned short y = __builtin_bit_cast(unsigned short, (bf16)b);
  return (u32)x | ((u32)y<<16);
}

// ---------------- workspace layout (bytes) ----------------
#define WS_NB   37748736          // nb fp32 [h][q][k] (pre-scaled by log2e)
#define WS_QKVG 40108032          // qkvg B-frag pack
#define WS_OP   40239104          // o_w pack
#define WS_KB   40271872          // K A-frag16 pairs bf16 [b][h][24x1KiB]; reused as wavg
#define WS_VB   78020608          // V B16-frags bf16 [b][h][24x1KiB] (masked rows zeroed)
#define WS_NEED 115769344

__device__ __forceinline__ void async_copy16(void* lds_dst, const void* gsrc){
  __builtin_amdgcn_global_load_lds((const __attribute__((address_space(1))) u32*)gsrc,
                                   (__attribute__((address_space(3))) u32*)lds_dst, 16, 0, 0);
}

// ---------------- K0: pre-pack weights into MFMA B-fragment order ----------------
// exp2-folding: q_w scaled by D^-0.5 * log2e; gating_w scaled by log2e.
// NOTE (v17): the same packed bytes serve as the A-operand of the transposed
// Q-projection (A-frag and B-frag share the (l15, g*8+j) lane structure).
__global__ __launch_bounds__(256) void pack_kernel(
    const float* __restrict__ qw, const float* __restrict__ kw,
    const float* __restrict__ vw, const float* __restrict__ gw,
    const float* __restrict__ ow, bf16* __restrict__ qkvg, bf16* __restrict__ op)
{
  int tid = blockIdx.x*256 + threadIdx.x;
  int lane = tid & 63, frag = tid >> 6;
  if (frag < 128) {                       // ((wm*4+h)*4+t)*2+f
    int f = frag & 1, t = (frag>>1)&3, h = (frag>>3)&3, wm = frag>>5;
    const float* W = wm==0?qw: (wm==1?kw: (wm==2?vw: gw));
    float sc = (wm==0) ? 0.17677669529663687f*LOG2E : (wm==3 ? LOG2E : 1.0f);
    int d = f*16 + (lane&15);
    #pragma unroll
    for (int j=0;j<8;j++){
      int c = t*32 + (lane>>4)*8 + j;
      qkvg[tid*8 + j] = (bf16)(W[c*128 + h*32 + d]*sc);
    }
  } else if (frag < 160) {                // o_w
    int fr = frag - 128, f = fr & 7, t = fr>>3;
    int c = f*16 + (lane&15);
    #pragma unroll
    for (int j=0;j<8;j++){
      int d = (lane>>4)*8 + j;
      op[(fr*64 + lane)*8 + j] = (bf16)ow[(t*32 + d)*128 + c];
    }
  }
}

// ---------------- K1: LayerNorm (fp32) -> x bf16, + nb_bias [h][q][k] * log2e ----------------
__global__ __launch_bounds__(256) void ln_kernel(
    const float* __restrict__ pa, const float* __restrict__ lns,
    const float* __restrict__ lnb, const float* __restrict__ fw,
    bf16* __restrict__ xout, float* __restrict__ nbout)
{
  int wid = (blockIdx.x*256 + threadIdx.x) >> 6;
  int lane = threadIdx.x & 63;
  int nw = (gridDim.x*256) >> 6;
  float2 sc = *(const float2*)(lns + lane*2);
  float2 bi = *(const float2*)(lnb + lane*2);
  float4 f0 = *(const float4*)(fw + lane*8);
  float4 f1 = *(const float4*)(fw + lane*8 + 4);
  for (int row = wid; row < NN*NN; row += nw){
    float2 v = *(const float2*)(pa + row*128 + lane*2);
    float s = v.x + v.y;
    float sq = v.x*v.x + v.y*v.y;
    #pragma unroll
    for (int m=1;m<64;m<<=1){ s += __shfl_xor(s,m); sq += __shfl_xor(sq,m); }
    float mu = s*(1.f/128.f);
    float rstd = rsqrtf(sq*(1.f/128.f) - mu*mu + 1e-5f);
    float x0 = (v.x-mu)*rstd*sc.x + bi.x;
    float x1 = (v.y-mu)*rstd*sc.y + bi.y;
    unsigned short h0 = __builtin_bit_cast(unsigned short, (bf16)x0);
    unsigned short h1 = __builtin_bit_cast(unsigned short, (bf16)x1);
    *(unsigned int*)((char*)xout + row*256 + lane*4) = ((unsigned int)h1<<16)|h0;
    float4 t;
    t.x = x0*f0.x + x1*f1.x;
    t.y = x0*f0.y + x1*f1.y;
    t.z = x0*f0.z + x1*f1.z;
    t.w = x0*f0.w + x1*f1.w;
    #pragma unroll
    for (int m=1;m<64;m<<=1){
      t.x += __shfl_xor(t.x,m); t.y += __shfl_xor(t.y,m);
      t.z += __shfl_xor(t.z,m); t.w += __shfl_xor(t.w,m);
    }
    float vsel = (lane==0)?t.x : (lane==1)?t.y : (lane==2)?t.z : t.w;
    if (lane < 4) nbout[(size_t)lane*(NN*NN) + row] = vsel*LOG2E;
  }
}

// ---------------- K2: K/V projection GEMM -> fragment-packed buffers ----------------
// K per (b,h,tau): TWO A-frag16 halves (v17): frag f: lane holds K[key=l15][d=f*16+4g+j],
//   8B/lane, 512B/frag, 1KiB total per tau (same footprint as before).
// V per (b,h,tau): B-frag16 pair: lane holds V[key=tau*16+4g+j][d=fh*16+l15], raw C/D accum.
__global__ __launch_bounds__(256) void proj_kv_kernel(
    const bf16* __restrict__ xg, const bf16* __restrict__ qkvg,
    const int* __restrict__ mask, bf16* __restrict__ kbuf, bf16* __restrict__ vbuf)
{
  __shared__ char psm[16384];
  const int w = threadIdx.x>>6, lane = threadIdx.x&63, g = (lane>>4)&3, l15 = lane&15;
  const int W = blockIdx.x*4 + w;
  const int rt = W>>1, wm = 1 + (W&1);
  const f32x4 Z = {0.f,0.f,0.f,0.f};
  f32x4 acc[8];
  #pragma unroll
  for (int f8=0;f8<8;f8++) acc[f8] = Z;
  const bf16* xrow = xg + (size_t)(rt*16 + l15)*CC;
  #pragma unroll
  for (int t=0;t<4;t++){
    bf16x8 a = *(const bf16x8*)(xrow + t*32 + g*8);
    #pragma unroll
    for (int f8=0; f8<8; f8++){
      int h = f8>>1, fh = f8&1;
      bf16x8 bb = *(const bf16x8*)(qkvg + (((wm*4+h)*4+t)*2+fh)*512 + lane*8);
      acc[f8] = MFMA16(a, bb, acc[f8]);
    }
  }
  const int bq = rt/24, tau = rt%24;
  if (wm==1){
    char* scr = psm + w*4096;
    #pragma unroll
    for (int f8=0; f8<8; f8++){
      #pragma unroll
      for (int j=0;j<4;j++){
        unsigned r = g*4+j;
        *(bf16*)(scr + ((r*256 + (f8*16+l15)*2) ^ (((r>>1)&7)<<4))) = (bf16)acc[f8][j];
      }
    }
    #pragma unroll
    for (int h=0;h<4;h++){
      // A-frag16 halves: f=0 -> d = h*32 + 4g+j (byte h*64 + g*8);
      //                  f=1 -> d = h*32 + 16 + 4g+j (byte h*64 + 32 + g*8)
      bf16x4v k0 = *(const bf16x4v*)(scr + ((l15*256 + h*64      + g*8) ^ (((l15>>1)&7)<<4)));
      bf16x4v k1 = *(const bf16x4v*)(scr + ((l15*256 + h*64 + 32 + g*8) ^ (((l15>>1)&7)<<4)));
      char* base = (char*)kbuf + (((size_t)(bq*4+h)*24 + tau)*1024);
      *(bf16x4v*)(base +       lane*8) = k0;
      *(bf16x4v*)(base + 512 + lane*8) = k1;
    }
  } else {
    // zero masked key rows (C/D row = key = tau*16 + 4g + j); belt+braces
    int4 mi = *(const int4*)(mask + bq*NN + tau*16 + g*4);
    float mb[4] = { mi.x?1.f:0.f, mi.y?1.f:0.f, mi.z?1.f:0.f, mi.w?1.f:0.f };
    #pragma unroll
    for (int f8=0; f8<8; f8++){
      #pragma unroll
      for (int j=0;j<4;j++) acc[f8][j] *= mb[j];
    }
    #pragma unroll
    for (int h=0;h<4;h++){
      f32x4 a0 = acc[h*2+0], a1 = acc[h*2+1];
      uint4 st4;
      st4.x = bpack(a0[0], a0[1]);
      st4.y = bpack(a0[2], a0[3]);
      st4.z = bpack(a1[0], a1[1]);
      st4.w = bpack(a1[2], a1[3]);
      *(uint4*)((char*)vbuf + ((size_t)(bq*4+h)*24 + tau)*1024 + lane*16) = st4;
    }
  }
}

// ---------------- K3: attention v17 ----------------
// = v12 (best measured: 182us attn) + Q-bounce elimination:
//  Q is projected TRANSPOSED (MFMA16 with the W-frag as A and x-frag as B ->
//  lane holds Q^T[d=4g+j][q=l15]), bf16-packed in-register, and consumed
//  directly as the B-frag16 of two chained 16x16x16 S^T MFMAs per key-frag
//  (K stored as A-frag16 halves). No LDS write/read/lgkm on the Q path.
//  nb as S-MFMA C-init; exp2-domain fixed-max softmax; bf16 mask bias.
//  waves_per_eu(2,4): the proven no-spill budget (min>=3 spills: r9/r16).
#define L17_SCR  49152            // 4 x 1 KiB per-wave scratch (wg bounce only)
#define L17_MASK 53248            // bf16 bias [384] (= log2e * 1e9 * (m-1))
#define L17_TOT  54016

__global__ __attribute__((amdgpu_flat_work_group_size(256,256), amdgpu_waves_per_eu(2,4)))
void attn_kernel17(
    const bf16* __restrict__ xg, const int* __restrict__ mask,
    const float* __restrict__ nb, const bf16* __restrict__ qkvg,
    bf16* __restrict__ kbuf, const bf16* __restrict__ vbuf,
    const float* __restrict__ gb)
{
  __shared__ char sm[L17_TOT];
  const int tid = threadIdx.x;
  const int lane = tid & 63, w = tid >> 6;
  const int g = (lane >> 4)&3, l15 = lane & 15;
  const f32x4 Z = {0.f,0.f,0.f,0.f};

  // h-major: concurrent blocks share one nb[h] plane (L2-resident)
  const u32 bid = blockIdx.x;
  const int h = bid / 384;
  const int b = bid - h*384;

  const char* kbh = (const char*)kbuf + ((size_t)b*4 + h)*24576;
  const char* vbh = (const char*)vbuf + ((size_t)b*4 + h)*24576;

  // ---- stage K (24KiB) + V (24KiB) + mask bias bf16 (768B) ----
  #pragma unroll
  for (int i=0;i<6;i++){
    unsigned u = (i*4 + w)*1024;
    async_copy16(sm + u,         kbh + u + lane*16);
    async_copy16(sm + 24576 + u, vbh + u + lane*16);
  }
  for (int k = tid; k < NN; k += 256)
    *(bf16*)(sm + L17_MASK + k*2) = (bf16)(1.44269504e9f*((float)mask[b*NN + k] - 1.0f));
  __syncthreads();   // vmcnt+lgkm drain; all staging visible

  const unsigned scb = L17_SCR + w*1024;
  const float* nbh = nb + (size_t)h*(NN*NN);

  for (int i=0;i<6;i++){
    const int qt = w*6 + i;
    const int qb = qt*16;

    // x A-frags for this q-tile (also valid as the B-operand of transposed proj)
    bf16x8 a4[4];
    #pragma unroll
    for (int t=0;t<4;t++)
      a4[t] = *(const bf16x8*)(xg + (size_t)(b*NN + qb + l15)*CC + t*32 + g*8);

    // ---- transposed Q projection: Qt_f = sum_t MFMA16(Wq_frag(f,t), a4[t]) ----
    // lane holds Q^T[d = f*16 + 4g+j][q = l15]  (fp32)
    f32x4 Qt0=Z, Qt1=Z;
    #pragma unroll
    for (int t=0;t<4;t++){
      bf16x8 wq0 = *(const bf16x8*)(qkvg + (((0*4+h)*4+t)*2+0)*512 + lane*8);
      bf16x8 wq1 = *(const bf16x8*)(qkvg + (((0*4+h)*4+t)*2+1)*512 + lane*8);
      Qt0 = MFMA16(wq0, a4[t], Qt0);
      Qt1 = MFMA16(wq1, a4[t], Qt1);
    }
    // pack to B-frag16s for S^T (k = d = 4g+j, n = q = l15)
    bf16x4v qb0 = {(bf16)Qt0[0], (bf16)Qt0[1], (bf16)Qt0[2], (bf16)Qt0[3]};
    bf16x4v qb1 = {(bf16)Qt1[0], (bf16)Qt1[1], (bf16)Qt1[2], (bf16)Qt1[3]};

    // ---- fixed-max softmax (exp2 domain) + register PV, six 64-key chunks ----
    float sum_ = 0.f;
    f32x4 o0=Z, o1=Z;
    const float* nbq = nbh + (size_t)(qb + l15)*NN;

    #pragma unroll
    for (int c=0;c<6;c++){
      f32x4 st[4];
      #pragma unroll
      for (int nf=0;nf<4;nf++){
        float4 nbv = *(const float4*)(nbq + c*64 + nf*16 + g*4);
        bf16x4v kA0 = *(const bf16x4v*)(sm + (c*4+nf)*1024 +       lane*8);
        bf16x4v kA1 = *(const bf16x4v*)(sm + (c*4+nf)*1024 + 512 + lane*8);
        f32x4 s0 = PVMFMA(as_pvab(kA0), qb0, __builtin_bit_cast(f32x4, nbv));
        st[nf]   = PVMFMA(as_pvab(kA1), qb1, s0);
      }
      #pragma unroll
      for (int nf=0;nf<4;nf++){
        bf16x4v mk4 = *(const bf16x4v*)(sm + L17_MASK + (c*64 + nf*16 + g*4)*2);
        #pragma unroll
        for (int j=0;j<4;j++){
          float pv = exp2f(st[nf][j] + (float)mk4[j] - 28.8539008178f); // == exp(S-20)
          st[nf][j] = pv;
          sum_ += pv;
        }
      }
      #pragma unroll
      for (int nf=0;nf<4;nf++){
        pvab_t pa = mk_pvab(bpack(st[nf][0], st[nf][1]), bpack(st[nf][2], st[nf][3]));
        bf16x8 vv = *(const bf16x8*)(sm + 24576 + (c*4+nf)*1024 + lane*16);
        bf16x4v vlo = {vv[0],vv[1],vv[2],vv[3]};
        bf16x4v vhi = {vv[4],vv[5],vv[6],vv[7]};
        o0 = PVMFMA(pa, vlo, o0);
        o1 = PVMFMA(pa, vhi, o1);
      }
    } // c

    // deferred cross-lane sum reduce + broadcast to C/D rows
    sum_ += __shfl_xor(sum_, 16);
    sum_ += __shfl_xor(sum_, 32);
    float rsl = 1.f/sum_;
    float rcd[4];
    #pragma unroll
    for (int j=0;j<4;j++)
      rcd[j] = __shfl(rsl, (lane & 0x30) + g*4 + j);

    // ---- gate projection (post-PV; normal orientation matches o's C/D layout) ----
    f32x4 g0=Z, g1=Z;
    #pragma unroll
    for (int t=0;t<4;t++){
      bf16x8 bg0 = *(const bf16x8*)(qkvg + (((3*4+h)*4+t)*2+0)*512 + lane*8);
      bf16x8 bg1 = *(const bf16x8*)(qkvg + (((3*4+h)*4+t)*2+1)*512 + lane*8);
      g0 = MFMA16(a4[t], bg0, g0);
      g1 = MFMA16(a4[t], bg1, g1);
    }

    // ---- wg = (O/s)*sigmoid; bounce to A-frag; store to wavg (kbuf region) ----
    #pragma unroll
    for (int f=0;f<2;f++){
      f32x4 ov = f ? o1 : o0, gv = f ? g1 : g0;
      int d = f*16 + l15;
      float gbv = gb[h*32 + d]*LOG2E;
      #pragma unroll
      for (int j=0;j<4;j++){
        float gt = 1.f/(1.f + exp2f(-(gv[j] + gbv)));
        float wg = ov[j]*rcd[j]*gt;
        unsigned r = g*4 + j, cb2 = (unsigned)d*2;
        *(bf16*)(sm + scb + ((r*64 + cb2) ^ (((r>>1)&7)<<4))) = (bf16)wg;
      }
    }
    bf16x8 awg = *(const bf16x8*)(sm + scb + ((l15*64 + g*16) ^ (((l15>>1)&7)<<4)));
    *(bf16x8*)((char*)kbuf + ((size_t)b*4 + h)*24576 + qt*1024 + lane*16) = awg;
  } // i (q-tiles)
}

// ---------------- K4: out-projection GEMM: out = wavg · o_w + ob ----------------
__global__ __launch_bounds__(256) void outproj_kernel(
    const bf16* __restrict__ wavg, const bf16* __restrict__ opk,
    const float* __restrict__ ob, float* __restrict__ out)
{
  const int w = threadIdx.x>>6, lane = threadIdx.x&63;
  const int g = (lane>>4)&3, l15 = lane&15;
  const f32x4 Z = {0.f,0.f,0.f,0.f};
  const int W = blockIdx.x*4 + w;
  const int b = W/24, qt = W%24, qb = qt*16;

  bf16x8 aw[4];
  #pragma unroll
  for (int h=0;h<4;h++)
    aw[h] = *(const bf16x8*)((const char*)wavg + ((size_t)b*4 + h)*24576 + qt*1024 + lane*16);

  f32x4 outa[8];
  #pragma unroll
  for (int nf=0;nf<8;nf++) outa[nf] = Z;
  #pragma unroll
  for (int h=0;h<4;h++){
    #pragma unroll
    for (int nf=0;nf<8;nf++){
      bf16x8 bo = *(const bf16x8*)(opk + ((h*8+nf)*64 + lane)*8);
      outa[nf] = MFMA16(aw[h], bo, outa[nf]);
    }
  }
  #pragma unroll
  for (int nf=0;nf<8;nf++){
    int c = nf*16 + l15;
    float obv = ob[c];
    #pragma unroll
    for (int j=0;j<4;j++){
      int qi = qb + g*4 + j;
      out[((size_t)b*NN + qi)*CC + c] = outa[nf][j] + obv;
    }
  }
}

extern "C" void kernel_launch(void* const* d_in, const int* in_sizes, int n_in,
                              void* d_out, int out_size, void* d_ws, size_t ws_size,
                              hipStream_t stream)
{
  (void)in_sizes; (void)n_in; (void)out_size; (void)ws_size;
  const float* pa  = (const float*)d_in[0];
  const int*   msk = (const int*)d_in[1];
  const float* lns = (const float*)d_in[2];
  const float* lnb = (const float*)d_in[3];
  const float* fw  = (const float*)d_in[4];
  const float* qw  = (const float*)d_in[5];
  const float* kw  = (const float*)d_in[6];
  const float* vw  = (const float*)d_in[7];
  const float* gw  = (const float*)d_in[8];
  const float* gbv = (const float*)d_in[9];
  const float* ow  = (const float*)d_in[10];
  const float* ob  = (const float*)d_in[11];
  float* out = (float*)d_out;

  char* ws = (char*)d_ws;
  bf16*  xbuf  = (bf16*)(ws);
  float* nbbuf = (float*)(ws + WS_NB);
  bf16*  qkvg  = (bf16*)(ws + WS_QKVG);
  bf16*  opk   = (bf16*)(ws + WS_OP);
  bf16*  kbuf  = (bf16*)(ws + WS_KB);
  bf16*  vbuf  = (bf16*)(ws + WS_VB);

  pack_kernel<<<40, 256, 0, stream>>>(qw, kw, vw, gw, ow, qkvg, opk);
  ln_kernel<<<1152, 256, 0, stream>>>(pa, lns, lnb, fw, xbuf, nbbuf);
  proj_kv_kernel<<<4608, 256, 0, stream>>>(xbuf, qkvg, msk, kbuf, vbuf);
  attn_kernel17<<<1536, 256, 0, stream>>>(xbuf, msk, nbbuf, qkvg, kbuf, vbuf, gbv);
  outproj_kernel<<<2304, 256, 0, stream>>>(kbuf, opk, ob, out);
}

// Round 18
// 295.594 us; speedup vs baseline: 1.3295x; 1.1303x over previous
//
#include <hip/hip_runtime.h>

typedef __bf16 bf16;
typedef __bf16 bf16x8 __attribute__((ext_vector_type(8)));
typedef __bf16 bf16x4v __attribute__((ext_vector_type(4)));
typedef short s16x4 __attribute__((ext_vector_type(4)));
typedef float f32x4 __attribute__((ext_vector_type(4)));
typedef unsigned int u32;
typedef unsigned long long u64;

#define NN 384
#define CC 128
#define LOG2E 1.44269504088896f

#define MFMA16(a,b,c) __builtin_amdgcn_mfma_f32_16x16x32_bf16(a,b,c,0,0,0)

// 16x16x16 bf16 MFMA
#if __has_builtin(__builtin_amdgcn_mfma_f32_16x16x16_bf16)
typedef bf16x4v pvab_t;
static __device__ __forceinline__ f32x4 PVMFMA(pvab_t A, bf16x4v B, f32x4 C){
  return __builtin_amdgcn_mfma_f32_16x16x16_bf16(A, B, C, 0,0,0);
}
#else
typedef s16x4 pvab_t;
static __device__ __forceinline__ f32x4 PVMFMA(pvab_t A, bf16x4v B, f32x4 C){
  return __builtin_amdgcn_mfma_f32_16x16x16bf16_1k(A, __builtin_bit_cast(s16x4, B), C, 0,0,0);
}
#endif
static __device__ __forceinline__ pvab_t mk_pvab(u32 w0, u32 w1){
  return __builtin_bit_cast(pvab_t, (u64)w0 | ((u64)w1<<32));
}

static __device__ __forceinline__ u32 bpack(float a, float b){
  unsigned short x = __builtin_bit_cast(unsigned short, (bf16)a);
  unsigned short y = __builtin_bit_cast(unsigned short, (bf16)b);
  return (u32)x | ((u32)y<<16);
}

// ---------------- workspace layout (bytes) ----------------
#define WS_NB   37748736          // nb fp32 [h][q][k] (pre-scaled by log2e)
#define WS_QKVG 40108032          // qkvg B-frag pack
#define WS_OP   40239104          // o_w pack
#define WS_KB   40271872          // K A-frag32 bf16 [b][h][24x1KiB]; reused as wavg
#define WS_VB   78020608          // V B16-frags bf16 [b][h][24x1KiB] (masked rows zeroed)
#define WS_NEED 115769344

__device__ __forceinline__ void async_copy16(void* lds_dst, const void* gsrc){
  __builtin_amdgcn_global_load_lds((const __attribute__((address_space(1))) u32*)gsrc,
                                   (__attribute__((address_space(3))) u32*)lds_dst, 16, 0, 0);
}

// ---------------- K0: pre-pack weights into MFMA B-fragment order ----------------
// exp2-folding: q_w scaled by D^-0.5 * log2e; gating_w scaled by log2e.
__global__ __launch_bounds__(256) void pack_kernel(
    const float* __restrict__ qw, const float* __restrict__ kw,
    const float* __restrict__ vw, const float* __restrict__ gw,
    const float* __restrict__ ow, bf16* __restrict__ qkvg, bf16* __restrict__ op)
{
  int tid = blockIdx.x*256 + threadIdx.x;
  int lane = tid & 63, frag = tid >> 6;
  if (frag < 128) {                       // ((wm*4+h)*4+t)*2+f
    int f = frag & 1, t = (frag>>1)&3, h = (frag>>3)&3, wm = frag>>5;
    const float* W = wm==0?qw: (wm==1?kw: (wm==2?vw: gw));
    float sc = (wm==0) ? 0.17677669529663687f*LOG2E : (wm==3 ? LOG2E : 1.0f);
    int d = f*16 + (lane&15);
    #pragma unroll
    for (int j=0;j<8;j++){
      int c = t*32 + (lane>>4)*8 + j;
      qkvg[tid*8 + j] = (bf16)(W[c*128 + h*32 + d]*sc);
    }
  } else if (frag < 160) {                // o_w
    int fr = frag - 128, f = fr & 7, t = fr>>3;
    int c = f*16 + (lane&15);
    #pragma unroll
    for (int j=0;j<8;j++){
      int d = (lane>>4)*8 + j;
      op[(fr*64 + lane)*8 + j] = (bf16)ow[(t*32 + d)*128 + c];
    }
  }
}

// ---------------- K1: LayerNorm (fp32) -> x bf16, + nb_bias [h][q][k] * log2e ----------------
__global__ __launch_bounds__(256) void ln_kernel(
    const float* __restrict__ pa, const float* __restrict__ lns,
    const float* __restrict__ lnb, const float* __restrict__ fw,
    bf16* __restrict__ xout, float* __restrict__ nbout)
{
  int wid = (blockIdx.x*256 + threadIdx.x) >> 6;
  int lane = threadIdx.x & 63;
  int nw = (gridDim.x*256) >> 6;
  float2 sc = *(const float2*)(lns + lane*2);
  float2 bi = *(const float2*)(lnb + lane*2);
  float4 f0 = *(const float4*)(fw + lane*8);
  float4 f1 = *(const float4*)(fw + lane*8 + 4);
  for (int row = wid; row < NN*NN; row += nw){
    float2 v = *(const float2*)(pa + row*128 + lane*2);
    float s = v.x + v.y;
    float sq = v.x*v.x + v.y*v.y;
    #pragma unroll
    for (int m=1;m<64;m<<=1){ s += __shfl_xor(s,m); sq += __shfl_xor(sq,m); }
    float mu = s*(1.f/128.f);
    float rstd = rsqrtf(sq*(1.f/128.f) - mu*mu + 1e-5f);
    float x0 = (v.x-mu)*rstd*sc.x + bi.x;
    float x1 = (v.y-mu)*rstd*sc.y + bi.y;
    unsigned short h0 = __builtin_bit_cast(unsigned short, (bf16)x0);
    unsigned short h1 = __builtin_bit_cast(unsigned short, (bf16)x1);
    *(unsigned int*)((char*)xout + row*256 + lane*4) = ((unsigned int)h1<<16)|h0;
    float4 t;
    t.x = x0*f0.x + x1*f1.x;
    t.y = x0*f0.y + x1*f1.y;
    t.z = x0*f0.z + x1*f1.z;
    t.w = x0*f0.w + x1*f1.w;
    #pragma unroll
    for (int m=1;m<64;m<<=1){
      t.x += __shfl_xor(t.x,m); t.y += __shfl_xor(t.y,m);
      t.z += __shfl_xor(t.z,m); t.w += __shfl_xor(t.w,m);
    }
    float vsel = (lane==0)?t.x : (lane==1)?t.y : (lane==2)?t.z : t.w;
    if (lane < 4) nbout[(size_t)lane*(NN*NN) + row] = vsel*LOG2E;
  }
}

// ---------------- K2: K/V projection GEMM -> fragment-packed buffers ----------------
// K per (b,h,tau): A-frag32: lane holds K[key=l15][d=g*8+j] (16B/lane, 1KiB/frag)
// V per (b,h,tau): B-frag16 pair: lane holds V[key=tau*16+4g+j][d=fh*16+l15]; masked rows zeroed.
__global__ __launch_bounds__(256) void proj_kv_kernel(
    const bf16* __restrict__ xg, const bf16* __restrict__ qkvg,
    const int* __restrict__ mask, bf16* __restrict__ kbuf, bf16* __restrict__ vbuf)
{
  __shared__ char psm[16384];
  const int w = threadIdx.x>>6, lane = threadIdx.x&63, g = (lane>>4)&3, l15 = lane&15;
  const int W = blockIdx.x*4 + w;
  const int rt = W>>1, wm = 1 + (W&1);
  const f32x4 Z = {0.f,0.f,0.f,0.f};
  f32x4 acc[8];
  #pragma unroll
  for (int f8=0;f8<8;f8++) acc[f8] = Z;
  const bf16* xrow = xg + (size_t)(rt*16 + l15)*CC;
  #pragma unroll
  for (int t=0;t<4;t++){
    bf16x8 a = *(const bf16x8*)(xrow + t*32 + g*8);
    #pragma unroll
    for (int f8=0; f8<8; f8++){
      int h = f8>>1, fh = f8&1;
      bf16x8 bb = *(const bf16x8*)(qkvg + (((wm*4+h)*4+t)*2+fh)*512 + lane*8);
      acc[f8] = MFMA16(a, bb, acc[f8]);
    }
  }
  const int bq = rt/24, tau = rt%24;
  if (wm==1){
    char* scr = psm + w*4096;
    #pragma unroll
    for (int f8=0; f8<8; f8++){
      #pragma unroll
      for (int j=0;j<4;j++){
        unsigned r = g*4+j;
        *(bf16*)(scr + ((r*256 + (f8*16+l15)*2) ^ (((r>>1)&7)<<4))) = (bf16)acc[f8][j];
      }
    }
    #pragma unroll
    for (int h=0;h<4;h++){
      bf16x8 kf = *(const bf16x8*)(scr + ((l15*256 + h*64 + g*16) ^ (((l15>>1)&7)<<4)));
      *(bf16x8*)(kbuf + (((size_t)(bq*4+h)*24 + tau)*64 + lane)*8) = kf;
    }
  } else {
    int4 mi = *(const int4*)(mask + bq*NN + tau*16 + g*4);
    float mb[4] = { mi.x?1.f:0.f, mi.y?1.f:0.f, mi.z?1.f:0.f, mi.w?1.f:0.f };
    #pragma unroll
    for (int f8=0; f8<8; f8++){
      #pragma unroll
      for (int j=0;j<4;j++) acc[f8][j] *= mb[j];
    }
    #pragma unroll
    for (int h=0;h<4;h++){
      f32x4 a0 = acc[h*2+0], a1 = acc[h*2+1];
      uint4 st4;
      st4.x = bpack(a0[0], a0[1]);
      st4.y = bpack(a0[2], a0[3]);
      st4.z = bpack(a1[0], a1[1]);
      st4.w = bpack(a1[2], a1[3]);
      *(uint4*)((char*)vbuf + ((size_t)(bq*4+h)*24 + tau)*1024 + lane*16) = st4;
    }
  }
}

// ---------------- K3: attention v18 = v12 + paired q-tiles (2-way intra-wave ILP) ----------------
// Counter-driven rationale: occupancy is hard-capped at 2 waves/EU (min>=3 spills:
// r9/r16); ~45% of cycles are unhidden latency in each wave's serial S->exp->PV
// chain. Two INDEPENDENT q-tiles per iteration give the scheduler interleavable
// chains, and K/V/weight/mask loads are shared across the pair (half the LDS
// reads per tile). Softmax pieces all individually validated: fixed-max exp2
// domain, nb as S-MFMA C-init, bf16 mask bias.
#define L18_SCR  49152            // 4 waves x 2 KiB scratch (1 KiB per tile slot)
#define L18_MASK 57344            // bf16 bias [384] (= log2e * 1e9 * (m-1))
#define L18_TOT  58112

__global__ __attribute__((amdgpu_flat_work_group_size(256,256), amdgpu_waves_per_eu(2,4)))
void attn_kernel18(
    const bf16* __restrict__ xg, const int* __restrict__ mask,
    const float* __restrict__ nb, const bf16* __restrict__ qkvg,
    bf16* __restrict__ kbuf, const bf16* __restrict__ vbuf,
    const float* __restrict__ gb)
{
  __shared__ char sm[L18_TOT];
  const int tid = threadIdx.x;
  const int lane = tid & 63, w = tid >> 6;
  const int g = (lane >> 4)&3, l15 = lane & 15;
  const f32x4 Z = {0.f,0.f,0.f,0.f};

  // h-major: concurrent blocks share one nb[h] plane (L2-resident)
  const u32 bid = blockIdx.x;
  const int h = bid / 384;
  const int b = bid - h*384;

  const char* kbh = (const char*)kbuf + ((size_t)b*4 + h)*24576;
  const char* vbh = (const char*)vbuf + ((size_t)b*4 + h)*24576;

  // ---- stage K (24KiB) + V (24KiB) + mask bias bf16 (768B) ----
  #pragma unroll
  for (int i=0;i<6;i++){
    unsigned u = (i*4 + w)*1024;
    async_copy16(sm + u,         kbh + u + lane*16);
    async_copy16(sm + 24576 + u, vbh + u + lane*16);
  }
  for (int k = tid; k < NN; k += 256)
    *(bf16*)(sm + L18_MASK + k*2) = (bf16)(1.44269504e9f*((float)mask[b*NN + k] - 1.0f));
  __syncthreads();   // vmcnt+lgkm drain; all staging visible

  const unsigned scbA = L18_SCR + w*2048;
  const unsigned scbB = scbA + 1024;
  const float* nbh = nb + (size_t)h*(NN*NN);

  for (int i=0;i<3;i++){
    const int qtA = w*6 + i*2, qtB = qtA + 1;
    const int qbA = qtA*16,    qbB = qtB*16;

    // x A-frags for both q-tiles
    bf16x8 a4A[4], a4B[4];
    #pragma unroll
    for (int t=0;t<4;t++){
      a4A[t] = *(const bf16x8*)(xg + (size_t)(b*NN + qbA + l15)*CC + t*32 + g*8);
      a4B[t] = *(const bf16x8*)(xg + (size_t)(b*NN + qbB + l15)*CC + t*32 + g*8);
    }

    // ---- Q projections (weight frags shared) ----
    f32x4 qA0=Z, qA1=Z, qB0=Z, qB1=Z;
    #pragma unroll
    for (int t=0;t<4;t++){
      bf16x8 bq0 = *(const bf16x8*)(qkvg + (((0*4+h)*4+t)*2+0)*512 + lane*8);
      bf16x8 bq1 = *(const bf16x8*)(qkvg + (((0*4+h)*4+t)*2+1)*512 + lane*8);
      qA0 = MFMA16(a4A[t], bq0, qA0);
      qA1 = MFMA16(a4A[t], bq1, qA1);
      qB0 = MFMA16(a4B[t], bq0, qB0);
      qB1 = MFMA16(a4B[t], bq1, qB1);
    }
    // bounce both Q accums -> B-frags (separate slots; independent lgkm chains)
    #pragma unroll
    for (int f=0;f<2;f++){
      f32x4 qqA = f ? qA1 : qA0, qqB = f ? qB1 : qB0;
      #pragma unroll
      for (int j=0;j<4;j++){
        unsigned r = g*4 + j, cb = (f*16 + l15)*2;
        unsigned off = (r*64 + cb) ^ (((r>>1)&7)<<4);
        *(bf16*)(sm + scbA + off) = (bf16)qqA[j];
        *(bf16*)(sm + scbB + off) = (bf16)qqB[j];
      }
    }
    unsigned aqoff = (l15*64 + g*16) ^ (((l15>>1)&7)<<4);
    bf16x8 aqA = *(const bf16x8*)(sm + scbA + aqoff);
    bf16x8 aqB = *(const bf16x8*)(sm + scbB + aqoff);

    // ---- dual fixed-max softmax + register PV, six 64-key chunks ----
    float sumA = 0.f, sumB = 0.f;
    f32x4 oA0=Z, oA1=Z, oB0=Z, oB1=Z;
    const float* nbqA = nbh + (size_t)(qbA + l15)*NN;
    const float* nbqB = nbh + (size_t)(qbB + l15)*NN;

    #pragma unroll
    for (int c=0;c<6;c++){
      f32x4 stA[4], stB[4];
      #pragma unroll
      for (int nf=0;nf<4;nf++){
        bf16x8 ka = *(const bf16x8*)(sm + (c*4+nf)*1024 + lane*16);   // shared
        float4 nbvA = *(const float4*)(nbqA + c*64 + nf*16 + g*4);
        float4 nbvB = *(const float4*)(nbqB + c*64 + nf*16 + g*4);
        stA[nf] = MFMA16(ka, aqA, __builtin_bit_cast(f32x4, nbvA));
        stB[nf] = MFMA16(ka, aqB, __builtin_bit_cast(f32x4, nbvB));
      }
      #pragma unroll
      for (int nf=0;nf<4;nf++){
        bf16x4v mk4 = *(const bf16x4v*)(sm + L18_MASK + (c*64 + nf*16 + g*4)*2);  // shared
        #pragma unroll
        for (int j=0;j<4;j++){
          float pvA = exp2f(stA[nf][j] + (float)mk4[j] - 28.8539008178f);
          float pvB = exp2f(stB[nf][j] + (float)mk4[j] - 28.8539008178f);
          stA[nf][j] = pvA; sumA += pvA;
          stB[nf][j] = pvB; sumB += pvB;
        }
      }
      #pragma unroll
      for (int nf=0;nf<4;nf++){
        bf16x8 vv = *(const bf16x8*)(sm + 24576 + (c*4+nf)*1024 + lane*16);   // shared
        bf16x4v vlo = {vv[0],vv[1],vv[2],vv[3]};
        bf16x4v vhi = {vv[4],vv[5],vv[6],vv[7]};
        pvab_t paA = mk_pvab(bpack(stA[nf][0], stA[nf][1]), bpack(stA[nf][2], stA[nf][3]));
        pvab_t paB = mk_pvab(bpack(stB[nf][0], stB[nf][1]), bpack(stB[nf][2], stB[nf][3]));
        oA0 = PVMFMA(paA, vlo, oA0);
        oB0 = PVMFMA(paB, vlo, oB0);
        oA1 = PVMFMA(paA, vhi, oA1);
        oB1 = PVMFMA(paB, vhi, oB1);
      }
    } // c

    // deferred cross-lane sum reduces + broadcast to C/D rows
    sumA += __shfl_xor(sumA, 16); sumA += __shfl_xor(sumA, 32);
    sumB += __shfl_xor(sumB, 16); sumB += __shfl_xor(sumB, 32);
    float rslA = 1.f/sumA, rslB = 1.f/sumB;
    float rcdA[4], rcdB[4];
    #pragma unroll
    for (int j=0;j<4;j++){
      int src = (lane & 0x30) + g*4 + j;
      rcdA[j] = __shfl(rslA, src);
      rcdB[j] = __shfl(rslB, src);
    }

    // ---- gate projections (weight frags shared) ----
    f32x4 gA0=Z, gA1=Z, gB0=Z, gB1=Z;
    #pragma unroll
    for (int t=0;t<4;t++){
      bf16x8 bg0 = *(const bf16x8*)(qkvg + (((3*4+h)*4+t)*2+0)*512 + lane*8);
      bf16x8 bg1 = *(const bf16x8*)(qkvg + (((3*4+h)*4+t)*2+1)*512 + lane*8);
      gA0 = MFMA16(a4A[t], bg0, gA0);
      gA1 = MFMA16(a4A[t], bg1, gA1);
      gB0 = MFMA16(a4B[t], bg0, gB0);
      gB1 = MFMA16(a4B[t], bg1, gB1);
    }

    // ---- wg = (O/s)*sigmoid; bounce to A-frag per slot; store both wavg ----
    #pragma unroll
    for (int f=0;f<2;f++){
      f32x4 ovA = f ? oA1 : oA0, gvA = f ? gA1 : gA0;
      f32x4 ovB = f ? oB1 : oB0, gvB = f ? gB1 : gB0;
      int d = f*16 + l15;
      float gbv = gb[h*32 + d]*LOG2E;
      #pragma unroll
      for (int j=0;j<4;j++){
        unsigned r = g*4 + j, cb2 = (unsigned)d*2;
        unsigned off = (r*64 + cb2) ^ (((r>>1)&7)<<4);
        float gtA = 1.f/(1.f + exp2f(-(gvA[j] + gbv)));
        float gtB = 1.f/(1.f + exp2f(-(gvB[j] + gbv)));
        *(bf16*)(sm + scbA + off) = (bf16)(ovA[j]*rcdA[j]*gtA);
        *(bf16*)(sm + scbB + off) = (bf16)(ovB[j]*rcdB[j]*gtB);
      }
    }
    bf16x8 awgA = *(const bf16x8*)(sm + scbA + aqoff);
    bf16x8 awgB = *(const bf16x8*)(sm + scbB + aqoff);
    *(bf16x8*)((char*)kbuf + ((size_t)b*4 + h)*24576 + qtA*1024 + lane*16) = awgA;
    *(bf16x8*)((char*)kbuf + ((size_t)b*4 + h)*24576 + qtB*1024 + lane*16) = awgB;
  } // i (q-tile pairs)
}

// ---------------- K4: out-projection GEMM: out = wavg · o_w + ob ----------------
__global__ __launch_bounds__(256) void outproj_kernel(
    const bf16* __restrict__ wavg, const bf16* __restrict__ opk,
    const float* __restrict__ ob, float* __restrict__ out)
{
  const int w = threadIdx.x>>6, lane = threadIdx.x&63;
  const int g = (lane>>4)&3, l15 = lane&15;
  const f32x4 Z = {0.f,0.f,0.f,0.f};
  const int W = blockIdx.x*4 + w;
  const int b = W/24, qt = W%24, qb = qt*16;

  bf16x8 aw[4];
  #pragma unroll
  for (int h=0;h<4;h++)
    aw[h] = *(const bf16x8*)((const char*)wavg + ((size_t)b*4 + h)*24576 + qt*1024 + lane*16);

  f32x4 outa[8];
  #pragma unroll
  for (int nf=0;nf<8;nf++) outa[nf] = Z;
  #pragma unroll
  for (int h=0;h<4;h++){
    #pragma unroll
    for (int nf=0;nf<8;nf++){
      bf16x8 bo = *(const bf16x8*)(opk + ((h*8+nf)*64 + lane)*8);
      outa[nf] = MFMA16(aw[h], bo, outa[nf]);
    }
  }
  #pragma unroll
  for (int nf=0;nf<8;nf++){
    int c = nf*16 + l15;
    float obv = ob[c];
    #pragma unroll
    for (int j=0;j<4;j++){
      int qi = qb + g*4 + j;
      out[((size_t)b*NN + qi)*CC + c] = outa[nf][j] + obv;
    }
  }
}

extern "C" void kernel_launch(void* const* d_in, const int* in_sizes, int n_in,
                              void* d_out, int out_size, void* d_ws, size_t ws_size,
                              hipStream_t stream)
{
  (void)in_sizes; (void)n_in; (void)out_size; (void)ws_size;
  const float* pa  = (const float*)d_in[0];
  const int*   msk = (const int*)d_in[1];
  const float* lns = (const float*)d_in[2];
  const float* lnb = (const float*)d_in[3];
  const float* fw  = (const float*)d_in[4];
  const float* qw  = (const float*)d_in[5];
  const float* kw  = (const float*)d_in[6];
  const float* vw  = (const float*)d_in[7];
  const float* gw  = (const float*)d_in[8];
  const float* gbv = (const float*)d_in[9];
  const float* ow  = (const float*)d_in[10];
  const float* ob  = (const float*)d_in[11];
  float* out = (float*)d_out;

  char* ws = (char*)d_ws;
  bf16*  xbuf  = (bf16*)(ws);
  float* nbbuf = (float*)(ws + WS_NB);
  bf16*  qkvg  = (bf16*)(ws + WS_QKVG);
  bf16*  opk   = (bf16*)(ws + WS_OP);
  bf16*  kbuf  = (bf16*)(ws + WS_KB);
  bf16*  vbuf  = (bf16*)(ws + WS_VB);

  pack_kernel<<<40, 256, 0, stream>>>(qw, kw, vw, gw, ow, qkvg, opk);
  ln_kernel<<<1152, 256, 0, stream>>>(pa, lns, lnb, fw, xbuf, nbbuf);
  proj_kv_kernel<<<4608, 256, 0, stream>>>(xbuf, qkvg, msk, kbuf, vbuf);
  attn_kernel18<<<1536, 256, 0, stream>>>(xbuf, msk, nbbuf, qkvg, kbuf, vbuf, gbv);
  outproj_kernel<<<2304, 256, 0, stream>>>(kbuf, opk, ob, out);
}

// Round 19
// 285.099 us; speedup vs baseline: 1.3784x; 1.0368x over previous
//
#include <hip/hip_runtime.h>

typedef __bf16 bf16;
typedef __bf16 bf16x8 __attribute__((ext_vector_type(8)));
typedef __bf16 bf16x4v __attribute__((ext_vector_type(4)));
typedef short s16x4 __attribute__((ext_vector_type(4)));
typedef float f32x4 __attribute__((ext_vector_type(4)));
typedef unsigned int u32;
typedef unsigned long long u64;

#define NN 384
#define CC 128
#define LOG2E 1.44269504088896f

#define MFMA16(a,b,c) __builtin_amdgcn_mfma_f32_16x16x32_bf16(a,b,c,0,0,0)

// 16x16x16 bf16 MFMA
#if __has_builtin(__builtin_amdgcn_mfma_f32_16x16x16_bf16)
typedef bf16x4v pvab_t;
static __device__ __forceinline__ f32x4 PVMFMA(pvab_t A, bf16x4v B, f32x4 C){
  return __builtin_amdgcn_mfma_f32_16x16x16_bf16(A, B, C, 0,0,0);
}
#else
typedef s16x4 pvab_t;
static __device__ __forceinline__ f32x4 PVMFMA(pvab_t A, bf16x4v B, f32x4 C){
  return __builtin_amdgcn_mfma_f32_16x16x16bf16_1k(A, __builtin_bit_cast(s16x4, B), C, 0,0,0);
}
#endif
static __device__ __forceinline__ pvab_t mk_pvab(u32 w0, u32 w1){
  return __builtin_bit_cast(pvab_t, (u64)w0 | ((u64)w1<<32));
}

static __device__ __forceinline__ u32 bpack(float a, float b){
  unsigned short x = __builtin_bit_cast(unsigned short, (bf16)a);
  unsigned short y = __builtin_bit_cast(unsigned short, (bf16)b);
  return (u32)x | ((u32)y<<16);
}

// ---------------- workspace layout (bytes) ----------------
#define WS_NB   37748736          // nb fp32 [h][q][k] (pre-scaled by log2e)
#define WS_QKVG 40108032          // qkvg B-frag pack
#define WS_OP   40239104          // o_w pack
#define WS_KB   40271872          // K A-frag32 bf16 [b][h][24x1KiB]; reused as wavg
#define WS_VB   78020608          // V B16-frags bf16 [b][h][24x1KiB] (masked rows ZEROED — required)
#define WS_NEED 115769344

__device__ __forceinline__ void async_copy16(void* lds_dst, const void* gsrc){
  __builtin_amdgcn_global_load_lds((const __attribute__((address_space(1))) u32*)gsrc,
                                   (__attribute__((address_space(3))) u32*)lds_dst, 16, 0, 0);
}

// ---------------- K0: pre-pack weights into MFMA B-fragment order ----------------
// exp2-folding: q_w scaled by D^-0.5 * log2e; gating_w scaled by log2e.
__global__ __launch_bounds__(256) void pack_kernel(
    const float* __restrict__ qw, const float* __restrict__ kw,
    const float* __restrict__ vw, const float* __restrict__ gw,
    const float* __restrict__ ow, bf16* __restrict__ qkvg, bf16* __restrict__ op)
{
  int tid = blockIdx.x*256 + threadIdx.x;
  int lane = tid & 63, frag = tid >> 6;
  if (frag < 128) {                       // ((wm*4+h)*4+t)*2+f
    int f = frag & 1, t = (frag>>1)&3, h = (frag>>3)&3, wm = frag>>5;
    const float* W = wm==0?qw: (wm==1?kw: (wm==2?vw: gw));
    float sc = (wm==0) ? 0.17677669529663687f*LOG2E : (wm==3 ? LOG2E : 1.0f);
    int d = f*16 + (lane&15);
    #pragma unroll
    for (int j=0;j<8;j++){
      int c = t*32 + (lane>>4)*8 + j;
      qkvg[tid*8 + j] = (bf16)(W[c*128 + h*32 + d]*sc);
    }
  } else if (frag < 160) {                // o_w
    int fr = frag - 128, f = fr & 7, t = fr>>3;
    int c = f*16 + (lane&15);
    #pragma unroll
    for (int j=0;j<8;j++){
      int d = (lane>>4)*8 + j;
      op[(fr*64 + lane)*8 + j] = (bf16)ow[(t*32 + d)*128 + c];
    }
  }
}

// ---------------- K1: LayerNorm (fp32) -> x bf16, + nb_bias [h][q][k] * log2e ----------------
__global__ __launch_bounds__(256) void ln_kernel(
    const float* __restrict__ pa, const float* __restrict__ lns,
    const float* __restrict__ lnb, const float* __restrict__ fw,
    bf16* __restrict__ xout, float* __restrict__ nbout)
{
  int wid = (blockIdx.x*256 + threadIdx.x) >> 6;
  int lane = threadIdx.x & 63;
  int nw = (gridDim.x*256) >> 6;
  float2 sc = *(const float2*)(lns + lane*2);
  float2 bi = *(const float2*)(lnb + lane*2);
  float4 f0 = *(const float4*)(fw + lane*8);
  float4 f1 = *(const float4*)(fw + lane*8 + 4);
  for (int row = wid; row < NN*NN; row += nw){
    float2 v = *(const float2*)(pa + row*128 + lane*2);
    float s = v.x + v.y;
    float sq = v.x*v.x + v.y*v.y;
    #pragma unroll
    for (int m=1;m<64;m<<=1){ s += __shfl_xor(s,m); sq += __shfl_xor(sq,m); }
    float mu = s*(1.f/128.f);
    float rstd = rsqrtf(sq*(1.f/128.f) - mu*mu + 1e-5f);
    float x0 = (v.x-mu)*rstd*sc.x + bi.x;
    float x1 = (v.y-mu)*rstd*sc.y + bi.y;
    unsigned short h0 = __builtin_bit_cast(unsigned short, (bf16)x0);
    unsigned short h1 = __builtin_bit_cast(unsigned short, (bf16)x1);
    *(unsigned int*)((char*)xout + row*256 + lane*4) = ((unsigned int)h1<<16)|h0;
    float4 t;
    t.x = x0*f0.x + x1*f1.x;
    t.y = x0*f0.y + x1*f1.y;
    t.z = x0*f0.z + x1*f1.z;
    t.w = x0*f0.w + x1*f1.w;
    #pragma unroll
    for (int m=1;m<64;m<<=1){
      t.x += __shfl_xor(t.x,m); t.y += __shfl_xor(t.y,m);
      t.z += __shfl_xor(t.z,m); t.w += __shfl_xor(t.w,m);
    }
    float vsel = (lane==0)?t.x : (lane==1)?t.y : (lane==2)?t.z : t.w;
    if (lane < 4) nbout[(size_t)lane*(NN*NN) + row] = vsel*LOG2E;
  }
}

// ---------------- K2: K/V projection GEMM -> fragment-packed buffers ----------------
// K per (b,h,tau): A-frag32: lane holds K[key=l15][d=g*8+j] (16B/lane, 1KiB/frag)
// V per (b,h,tau): B-frag16 pair: lane holds V[key=tau*16+4g+j][d=fh*16+l15].
// Masked V ROWS ZEROED (required: v19 drops the mask bias from S entirely).
__global__ __launch_bounds__(256) void proj_kv_kernel(
    const bf16* __restrict__ xg, const bf16* __restrict__ qkvg,
    const int* __restrict__ mask, bf16* __restrict__ kbuf, bf16* __restrict__ vbuf)
{
  __shared__ char psm[16384];
  const int w = threadIdx.x>>6, lane = threadIdx.x&63, g = (lane>>4)&3, l15 = lane&15;
  const int W = blockIdx.x*4 + w;
  const int rt = W>>1, wm = 1 + (W&1);
  const f32x4 Z = {0.f,0.f,0.f,0.f};
  f32x4 acc[8];
  #pragma unroll
  for (int f8=0;f8<8;f8++) acc[f8] = Z;
  const bf16* xrow = xg + (size_t)(rt*16 + l15)*CC;
  #pragma unroll
  for (int t=0;t<4;t++){
    bf16x8 a = *(const bf16x8*)(xrow + t*32 + g*8);
    #pragma unroll
    for (int f8=0; f8<8; f8++){
      int h = f8>>1, fh = f8&1;
      bf16x8 bb = *(const bf16x8*)(qkvg + (((wm*4+h)*4+t)*2+fh)*512 + lane*8);
      acc[f8] = MFMA16(a, bb, acc[f8]);
    }
  }
  const int bq = rt/24, tau = rt%24;
  if (wm==1){
    char* scr = psm + w*4096;
    #pragma unroll
    for (int f8=0; f8<8; f8++){
      #pragma unroll
      for (int j=0;j<4;j++){
        unsigned r = g*4+j;
        *(bf16*)(scr + ((r*256 + (f8*16+l15)*2) ^ (((r>>1)&7)<<4))) = (bf16)acc[f8][j];
      }
    }
    #pragma unroll
    for (int h=0;h<4;h++){
      bf16x8 kf = *(const bf16x8*)(scr + ((l15*256 + h*64 + g*16) ^ (((l15>>1)&7)<<4)));
      *(bf16x8*)(kbuf + (((size_t)(bq*4+h)*24 + tau)*64 + lane)*8) = kf;
    }
  } else {
    int4 mi = *(const int4*)(mask + bq*NN + tau*16 + g*4);
    float mb[4] = { mi.x?1.f:0.f, mi.y?1.f:0.f, mi.z?1.f:0.f, mi.w?1.f:0.f };
    #pragma unroll
    for (int f8=0; f8<8; f8++){
      #pragma unroll
      for (int j=0;j<4;j++) acc[f8][j] *= mb[j];
    }
    #pragma unroll
    for (int h=0;h<4;h++){
      f32x4 a0 = acc[h*2+0], a1 = acc[h*2+1];
      uint4 st4;
      st4.x = bpack(a0[0], a0[1]);
      st4.y = bpack(a0[2], a0[3]);
      st4.z = bpack(a1[0], a1[1]);
      st4.w = bpack(a1[2], a1[3]);
      *(uint4*)((char*)vbuf + ((size_t)(bq*4+h)*24 + tau)*1024 + lane*16) = st4;
    }
  }
}

// ---------------- K3: attention v19 = v18 + mask-fold ----------------
// Counter-driven (v18: VALUBusy 53%, MfmaUtil 12.5% -> VALU-bound): delete the
// mask-bias add from the softmax stream. Masked keys' V rows are zeroed in
// proj_kv (o exact without mask); the denominator uses sum += P*mkf (one
// v_fmac with fp32 0/1 mask) instead of bias-add + exp + add. Masked P is
// bounded (<=~2e-4) and excluded exactly from both o and sum.
// Saves 16 v_add per chunk per tile (~20% of softmax VALU).
#define L19_SCR  49152            // 4 waves x 2 KiB scratch (1 KiB per tile slot)
#define L19_MASK 57344            // fp32 0/1 [384]
#define L19_TOT  58880

__global__ __attribute__((amdgpu_flat_work_group_size(256,256), amdgpu_waves_per_eu(2,4)))
void attn_kernel19(
    const bf16* __restrict__ xg, const int* __restrict__ mask,
    const float* __restrict__ nb, const bf16* __restrict__ qkvg,
    bf16* __restrict__ kbuf, const bf16* __restrict__ vbuf,
    const float* __restrict__ gb)
{
  __shared__ char sm[L19_TOT];
  const int tid = threadIdx.x;
  const int lane = tid & 63, w = tid >> 6;
  const int g = (lane >> 4)&3, l15 = lane & 15;
  const f32x4 Z = {0.f,0.f,0.f,0.f};

  // h-major: concurrent blocks share one nb[h] plane (L2-resident)
  const u32 bid = blockIdx.x;
  const int h = bid / 384;
  const int b = bid - h*384;

  const char* kbh = (const char*)kbuf + ((size_t)b*4 + h)*24576;
  const char* vbh = (const char*)vbuf + ((size_t)b*4 + h)*24576;

  // ---- stage K (24KiB) + V (24KiB) + mask 0/1 fp32 (1.5KiB) ----
  #pragma unroll
  for (int i=0;i<6;i++){
    unsigned u = (i*4 + w)*1024;
    async_copy16(sm + u,         kbh + u + lane*16);
    async_copy16(sm + 24576 + u, vbh + u + lane*16);
  }
  for (int k = tid; k < NN; k += 256)
    *(float*)(sm + L19_MASK + k*4) = (mask[b*NN + k] != 0) ? 1.f : 0.f;
  __syncthreads();   // vmcnt+lgkm drain; all staging visible

  const unsigned scbA = L19_SCR + w*2048;
  const unsigned scbB = scbA + 1024;
  const float* nbh = nb + (size_t)h*(NN*NN);

  for (int i=0;i<3;i++){
    const int qtA = w*6 + i*2, qtB = qtA + 1;
    const int qbA = qtA*16,    qbB = qtB*16;

    // x A-frags for both q-tiles
    bf16x8 a4A[4], a4B[4];
    #pragma unroll
    for (int t=0;t<4;t++){
      a4A[t] = *(const bf16x8*)(xg + (size_t)(b*NN + qbA + l15)*CC + t*32 + g*8);
      a4B[t] = *(const bf16x8*)(xg + (size_t)(b*NN + qbB + l15)*CC + t*32 + g*8);
    }

    // ---- Q projections (weight frags shared) ----
    f32x4 qA0=Z, qA1=Z, qB0=Z, qB1=Z;
    #pragma unroll
    for (int t=0;t<4;t++){
      bf16x8 bq0 = *(const bf16x8*)(qkvg + (((0*4+h)*4+t)*2+0)*512 + lane*8);
      bf16x8 bq1 = *(const bf16x8*)(qkvg + (((0*4+h)*4+t)*2+1)*512 + lane*8);
      qA0 = MFMA16(a4A[t], bq0, qA0);
      qA1 = MFMA16(a4A[t], bq1, qA1);
      qB0 = MFMA16(a4B[t], bq0, qB0);
      qB1 = MFMA16(a4B[t], bq1, qB1);
    }
    // bounce both Q accums -> B-frags (separate slots; independent lgkm chains)
    #pragma unroll
    for (int f=0;f<2;f++){
      f32x4 qqA = f ? qA1 : qA0, qqB = f ? qB1 : qB0;
      #pragma unroll
      for (int j=0;j<4;j++){
        unsigned r = g*4 + j, cb = (f*16 + l15)*2;
        unsigned off = (r*64 + cb) ^ (((r>>1)&7)<<4);
        *(bf16*)(sm + scbA + off) = (bf16)qqA[j];
        *(bf16*)(sm + scbB + off) = (bf16)qqB[j];
      }
    }
    unsigned aqoff = (l15*64 + g*16) ^ (((l15>>1)&7)<<4);
    bf16x8 aqA = *(const bf16x8*)(sm + scbA + aqoff);
    bf16x8 aqB = *(const bf16x8*)(sm + scbB + aqoff);

    // ---- dual fixed-max softmax (no mask add) + register PV, six 64-key chunks ----
    float sumA = 0.f, sumB = 0.f;
    f32x4 oA0=Z, oA1=Z, oB0=Z, oB1=Z;
    const float* nbqA = nbh + (size_t)(qbA + l15)*NN;
    const float* nbqB = nbh + (size_t)(qbB + l15)*NN;

    #pragma unroll
    for (int c=0;c<6;c++){
      f32x4 stA[4], stB[4];
      #pragma unroll
      for (int nf=0;nf<4;nf++){
        bf16x8 ka = *(const bf16x8*)(sm + (c*4+nf)*1024 + lane*16);   // shared
        float4 nbvA = *(const float4*)(nbqA + c*64 + nf*16 + g*4);
        float4 nbvB = *(const float4*)(nbqB + c*64 + nf*16 + g*4);
        stA[nf] = MFMA16(ka, aqA, __builtin_bit_cast(f32x4, nbvA));
        stB[nf] = MFMA16(ka, aqB, __builtin_bit_cast(f32x4, nbvB));
      }
      #pragma unroll
      for (int nf=0;nf<4;nf++){
        float4 mkf = *(const float4*)(sm + L19_MASK + (c*64 + nf*16 + g*4)*4);  // shared 0/1
        const float* mk = &mkf.x;
        #pragma unroll
        for (int j=0;j<4;j++){
          float pvA = exp2f(stA[nf][j] - 28.8539008178f);   // == exp(S - 20), no mask term
          float pvB = exp2f(stB[nf][j] - 28.8539008178f);
          stA[nf][j] = pvA; sumA += pvA*mk[j];              // masked keys excluded via fmac
          stB[nf][j] = pvB; sumB += pvB*mk[j];
        }
      }
      #pragma unroll
      for (int nf=0;nf<4;nf++){
        bf16x8 vv = *(const bf16x8*)(sm + 24576 + (c*4+nf)*1024 + lane*16);   // shared (masked rows = 0)
        bf16x4v vlo = {vv[0],vv[1],vv[2],vv[3]};
        bf16x4v vhi = {vv[4],vv[5],vv[6],vv[7]};
        pvab_t paA = mk_pvab(bpack(stA[nf][0], stA[nf][1]), bpack(stA[nf][2], stA[nf][3]));
        pvab_t paB = mk_pvab(bpack(stB[nf][0], stB[nf][1]), bpack(stB[nf][2], stB[nf][3]));
        oA0 = PVMFMA(paA, vlo, oA0);
        oB0 = PVMFMA(paB, vlo, oB0);
        oA1 = PVMFMA(paA, vhi, oA1);
        oB1 = PVMFMA(paB, vhi, oB1);
      }
    } // c

    // deferred cross-lane sum reduces + broadcast to C/D rows
    sumA += __shfl_xor(sumA, 16); sumA += __shfl_xor(sumA, 32);
    sumB += __shfl_xor(sumB, 16); sumB += __shfl_xor(sumB, 32);
    float rslA = 1.f/sumA, rslB = 1.f/sumB;
    float rcdA[4], rcdB[4];
    #pragma unroll
    for (int j=0;j<4;j++){
      int src = (lane & 0x30) + g*4 + j;
      rcdA[j] = __shfl(rslA, src);
      rcdB[j] = __shfl(rslB, src);
    }

    // ---- gate projections (weight frags shared) ----
    f32x4 gA0=Z, gA1=Z, gB0=Z, gB1=Z;
    #pragma unroll
    for (int t=0;t<4;t++){
      bf16x8 bg0 = *(const bf16x8*)(qkvg + (((3*4+h)*4+t)*2+0)*512 + lane*8);
      bf16x8 bg1 = *(const bf16x8*)(qkvg + (((3*4+h)*4+t)*2+1)*512 + lane*8);
      gA0 = MFMA16(a4A[t], bg0, gA0);
      gA1 = MFMA16(a4A[t], bg1, gA1);
      gB0 = MFMA16(a4B[t], bg0, gB0);
      gB1 = MFMA16(a4B[t], bg1, gB1);
    }

    // ---- wg = (O/s)*sigmoid; bounce to A-frag per slot; store both wavg ----
    #pragma unroll
    for (int f=0;f<2;f++){
      f32x4 ovA = f ? oA1 : oA0, gvA = f ? gA1 : gA0;
      f32x4 ovB = f ? oB1 : oB0, gvB = f ? gB1 : gB0;
      int d = f*16 + l15;
      float gbv = gb[h*32 + d]*LOG2E;
      #pragma unroll
      for (int j=0;j<4;j++){
        unsigned r = g*4 + j, cb2 = (unsigned)d*2;
        unsigned off = (r*64 + cb2) ^ (((r>>1)&7)<<4);
        float gtA = 1.f/(1.f + exp2f(-(gvA[j] + gbv)));
        float gtB = 1.f/(1.f + exp2f(-(gvB[j] + gbv)));
        *(bf16*)(sm + scbA + off) = (bf16)(ovA[j]*rcdA[j]*gtA);
        *(bf16*)(sm + scbB + off) = (bf16)(ovB[j]*rcdB[j]*gtB);
      }
    }
    bf16x8 awgA = *(const bf16x8*)(sm + scbA + aqoff);
    bf16x8 awgB = *(const bf16x8*)(sm + scbB + aqoff);
    *(bf16x8*)((char*)kbuf + ((size_t)b*4 + h)*24576 + qtA*1024 + lane*16) = awgA;
    *(bf16x8*)((char*)kbuf + ((size_t)b*4 + h)*24576 + qtB*1024 + lane*16) = awgB;
  } // i (q-tile pairs)
}

// ---------------- K4: out-projection GEMM: out = wavg · o_w + ob ----------------
__global__ __launch_bounds__(256) void outproj_kernel(
    const bf16* __restrict__ wavg, const bf16* __restrict__ opk,
    const float* __restrict__ ob, float* __restrict__ out)
{
  const int w = threadIdx.x>>6, lane = threadIdx.x&63;
  const int g = (lane>>4)&3, l15 = lane&15;
  const f32x4 Z = {0.f,0.f,0.f,0.f};
  const int W = blockIdx.x*4 + w;
  const int b = W/24, qt = W%24, qb = qt*16;

  bf16x8 aw[4];
  #pragma unroll
  for (int h=0;h<4;h++)
    aw[h] = *(const bf16x8*)((const char*)wavg + ((size_t)b*4 + h)*24576 + qt*1024 + lane*16);

  f32x4 outa[8];
  #pragma unroll
  for (int nf=0;nf<8;nf++) outa[nf] = Z;
  #pragma unroll
  for (int h=0;h<4;h++){
    #pragma unroll
    for (int nf=0;nf<8;nf++){
      bf16x8 bo = *(const bf16x8*)(opk + ((h*8+nf)*64 + lane)*8);
      outa[nf] = MFMA16(aw[h], bo, outa[nf]);
    }
  }
  #pragma unroll
  for (int nf=0;nf<8;nf++){
    int c = nf*16 + l15;
    float obv = ob[c];
    #pragma unroll
    for (int j=0;j<4;j++){
      int qi = qb + g*4 + j;
      out[((size_t)b*NN + qi)*CC + c] = outa[nf][j] + obv;
    }
  }
}

extern "C" void kernel_launch(void* const* d_in, const int* in_sizes, int n_in,
                              void* d_out, int out_size, void* d_ws, size_t ws_size,
                              hipStream_t stream)
{
  (void)in_sizes; (void)n_in; (void)out_size; (void)ws_size;
  const float* pa  = (const float*)d_in[0];
  const int*   msk = (const int*)d_in[1];
  const float* lns = (const float*)d_in[2];
  const float* lnb = (const float*)d_in[3];
  const float* fw  = (const float*)d_in[4];
  const float* qw  = (const float*)d_in[5];
  const float* kw  = (const float*)d_in[6];
  const float* vw  = (const float*)d_in[7];
  const float* gw  = (const float*)d_in[8];
  const float* gbv = (const float*)d_in[9];
  const float* ow  = (const float*)d_in[10];
  const float* ob  = (const float*)d_in[11];
  float* out = (float*)d_out;

  char* ws = (char*)d_ws;
  bf16*  xbuf  = (bf16*)(ws);
  float* nbbuf = (float*)(ws + WS_NB);
  bf16*  qkvg  = (bf16*)(ws + WS_QKVG);
  bf16*  opk   = (bf16*)(ws + WS_OP);
  bf16*  kbuf  = (bf16*)(ws + WS_KB);
  bf16*  vbuf  = (bf16*)(ws + WS_VB);

  pack_kernel<<<40, 256, 0, stream>>>(qw, kw, vw, gw, ow, qkvg, opk);
  ln_kernel<<<1152, 256, 0, stream>>>(pa, lns, lnb, fw, xbuf, nbbuf);
  proj_kv_kernel<<<4608, 256, 0, stream>>>(xbuf, qkvg, msk, kbuf, vbuf);
  attn_kernel19<<<1536, 256, 0, stream>>>(xbuf, msk, nbbuf, qkvg, kbuf, vbuf, gbv);
  outproj_kernel<<<2304, 256, 0, stream>>>(kbuf, opk, ob, out);
}

// Round 20
// 269.932 us; speedup vs baseline: 1.4559x; 1.0562x over previous
//
#include <hip/hip_runtime.h>

typedef __bf16 bf16;
typedef __bf16 bf16x8 __attribute__((ext_vector_type(8)));
typedef __bf16 bf16x4v __attribute__((ext_vector_type(4)));
typedef short s16x4 __attribute__((ext_vector_type(4)));
typedef float f32x4 __attribute__((ext_vector_type(4)));
typedef unsigned int u32;
typedef unsigned long long u64;

#define NN 384
#define CC 128
#define LOG2E 1.44269504088896f

#define MFMA16(a,b,c) __builtin_amdgcn_mfma_f32_16x16x32_bf16(a,b,c,0,0,0)

// native transcendentals (guarded rcp/exp sequences cost ~6-10 VALU ops each)
#if __has_builtin(__builtin_amdgcn_exp2f)
#define FEXP2(x) __builtin_amdgcn_exp2f(x)
#else
#define FEXP2(x) exp2f(x)
#endif
#define FRCP(x)  __builtin_amdgcn_rcpf(x)

// 16x16x16 bf16 MFMA
#if __has_builtin(__builtin_amdgcn_mfma_f32_16x16x16_bf16)
typedef bf16x4v pvab_t;
static __device__ __forceinline__ f32x4 PVMFMA(pvab_t A, bf16x4v B, f32x4 C){
  return __builtin_amdgcn_mfma_f32_16x16x16_bf16(A, B, C, 0,0,0);
}
#else
typedef s16x4 pvab_t;
static __device__ __forceinline__ f32x4 PVMFMA(pvab_t A, bf16x4v B, f32x4 C){
  return __builtin_amdgcn_mfma_f32_16x16x16bf16_1k(A, __builtin_bit_cast(s16x4, B), C, 0,0,0);
}
#endif
static __device__ __forceinline__ pvab_t mk_pvab(u32 w0, u32 w1){
  return __builtin_bit_cast(pvab_t, (u64)w0 | ((u64)w1<<32));
}

static __device__ __forceinline__ u32 bpack(float a, float b){
  unsigned short x = __builtin_bit_cast(unsigned short, (bf16)a);
  unsigned short y = __builtin_bit_cast(unsigned short, (bf16)b);
  return (u32)x | ((u32)y<<16);
}

// ---------------- workspace layout (bytes) ----------------
#define WS_NB   37748736          // nb fp32 [h][q][k] (pre-scaled by log2e)
#define WS_QKVG 40108032          // qkvg B-frag pack
#define WS_OP   40239104          // o_w pack
#define WS_KB   40271872          // K A-frag32 bf16 [b][h][24x1KiB]; reused as wavg
#define WS_VB   78020608          // V B16-frags bf16 [b][h][24x1KiB] (masked rows ZEROED — required)
#define WS_NEED 115769344

__device__ __forceinline__ void async_copy16(void* lds_dst, const void* gsrc){
  __builtin_amdgcn_global_load_lds((const __attribute__((address_space(1))) u32*)gsrc,
                                   (__attribute__((address_space(3))) u32*)lds_dst, 16, 0, 0);
}

// ---------------- K0: pre-pack weights into MFMA B-fragment order ----------------
// exp2-folding: q_w scaled by D^-0.5 * log2e; gating_w scaled by log2e.
__global__ __launch_bounds__(256) void pack_kernel(
    const float* __restrict__ qw, const float* __restrict__ kw,
    const float* __restrict__ vw, const float* __restrict__ gw,
    const float* __restrict__ ow, bf16* __restrict__ qkvg, bf16* __restrict__ op)
{
  int tid = blockIdx.x*256 + threadIdx.x;
  int lane = tid & 63, frag = tid >> 6;
  if (frag < 128) {                       // ((wm*4+h)*4+t)*2+f
    int f = frag & 1, t = (frag>>1)&3, h = (frag>>3)&3, wm = frag>>5;
    const float* W = wm==0?qw: (wm==1?kw: (wm==2?vw: gw));
    float sc = (wm==0) ? 0.17677669529663687f*LOG2E : (wm==3 ? LOG2E : 1.0f);
    int d = f*16 + (lane&15);
    #pragma unroll
    for (int j=0;j<8;j++){
      int c = t*32 + (lane>>4)*8 + j;
      qkvg[tid*8 + j] = (bf16)(W[c*128 + h*32 + d]*sc);
    }
  } else if (frag < 160) {                // o_w
    int fr = frag - 128, f = fr & 7, t = fr>>3;
    int c = f*16 + (lane&15);
    #pragma unroll
    for (int j=0;j<8;j++){
      int d = (lane>>4)*8 + j;
      op[(fr*64 + lane)*8 + j] = (bf16)ow[(t*32 + d)*128 + c];
    }
  }
}

// ---------------- K1: LayerNorm (fp32) -> x bf16, + nb_bias [h][q][k] * log2e ----------------
__global__ __launch_bounds__(256) void ln_kernel(
    const float* __restrict__ pa, const float* __restrict__ lns,
    const float* __restrict__ lnb, const float* __restrict__ fw,
    bf16* __restrict__ xout, float* __restrict__ nbout)
{
  int wid = (blockIdx.x*256 + threadIdx.x) >> 6;
  int lane = threadIdx.x & 63;
  int nw = (gridDim.x*256) >> 6;
  float2 sc = *(const float2*)(lns + lane*2);
  float2 bi = *(const float2*)(lnb + lane*2);
  float4 f0 = *(const float4*)(fw + lane*8);
  float4 f1 = *(const float4*)(fw + lane*8 + 4);
  for (int row = wid; row < NN*NN; row += nw){
    float2 v = *(const float2*)(pa + row*128 + lane*2);
    float s = v.x + v.y;
    float sq = v.x*v.x + v.y*v.y;
    #pragma unroll
    for (int m=1;m<64;m<<=1){ s += __shfl_xor(s,m); sq += __shfl_xor(sq,m); }
    float mu = s*(1.f/128.f);
    float rstd = rsqrtf(sq*(1.f/128.f) - mu*mu + 1e-5f);
    float x0 = (v.x-mu)*rstd*sc.x + bi.x;
    float x1 = (v.y-mu)*rstd*sc.y + bi.y;
    unsigned short h0 = __builtin_bit_cast(unsigned short, (bf16)x0);
    unsigned short h1 = __builtin_bit_cast(unsigned short, (bf16)x1);
    *(unsigned int*)((char*)xout + row*256 + lane*4) = ((unsigned int)h1<<16)|h0;
    float4 t;
    t.x = x0*f0.x + x1*f1.x;
    t.y = x0*f0.y + x1*f1.y;
    t.z = x0*f0.z + x1*f1.z;
    t.w = x0*f0.w + x1*f1.w;
    #pragma unroll
    for (int m=1;m<64;m<<=1){
      t.x += __shfl_xor(t.x,m); t.y += __shfl_xor(t.y,m);
      t.z += __shfl_xor(t.z,m); t.w += __shfl_xor(t.w,m);
    }
    float vsel = (lane==0)?t.x : (lane==1)?t.y : (lane==2)?t.z : t.w;
    if (lane < 4) nbout[(size_t)lane*(NN*NN) + row] = vsel*LOG2E;
  }
}

// ---------------- K2: K/V projection GEMM -> fragment-packed buffers ----------------
// K per (b,h,tau): A-frag32: lane holds K[key=l15][d=g*8+j] (16B/lane, 1KiB/frag)
// V per (b,h,tau): B-frag16 pair: lane holds V[key=tau*16+4g+j][d=fh*16+l15].
// Masked V ROWS ZEROED (required: mask bias dropped from S entirely).
__global__ __launch_bounds__(256) void proj_kv_kernel(
    const bf16* __restrict__ xg, const bf16* __restrict__ qkvg,
    const int* __restrict__ mask, bf16* __restrict__ kbuf, bf16* __restrict__ vbuf)
{
  __shared__ char psm[16384];
  const int w = threadIdx.x>>6, lane = threadIdx.x&63, g = (lane>>4)&3, l15 = lane&15;
  const int W = blockIdx.x*4 + w;
  const int rt = W>>1, wm = 1 + (W&1);
  const f32x4 Z = {0.f,0.f,0.f,0.f};
  f32x4 acc[8];
  #pragma unroll
  for (int f8=0;f8<8;f8++) acc[f8] = Z;
  const bf16* xrow = xg + (size_t)(rt*16 + l15)*CC;
  #pragma unroll
  for (int t=0;t<4;t++){
    bf16x8 a = *(const bf16x8*)(xrow + t*32 + g*8);
    #pragma unroll
    for (int f8=0; f8<8; f8++){
      int h = f8>>1, fh = f8&1;
      bf16x8 bb = *(const bf16x8*)(qkvg + (((wm*4+h)*4+t)*2+fh)*512 + lane*8);
      acc[f8] = MFMA16(a, bb, acc[f8]);
    }
  }
  const int bq = rt/24, tau = rt%24;
  if (wm==1){
    char* scr = psm + w*4096;
    #pragma unroll
    for (int f8=0; f8<8; f8++){
      #pragma unroll
      for (int j=0;j<4;j++){
        unsigned r = g*4+j;
        *(bf16*)(scr + ((r*256 + (f8*16+l15)*2) ^ (((r>>1)&7)<<4))) = (bf16)acc[f8][j];
      }
    }
    #pragma unroll
    for (int h=0;h<4;h++){
      bf16x8 kf = *(const bf16x8*)(scr + ((l15*256 + h*64 + g*16) ^ (((l15>>1)&7)<<4)));
      *(bf16x8*)(kbuf + (((size_t)(bq*4+h)*24 + tau)*64 + lane)*8) = kf;
    }
  } else {
    int4 mi = *(const int4*)(mask + bq*NN + tau*16 + g*4);
    float mb[4] = { mi.x?1.f:0.f, mi.y?1.f:0.f, mi.z?1.f:0.f, mi.w?1.f:0.f };
    #pragma unroll
    for (int f8=0; f8<8; f8++){
      #pragma unroll
      for (int j=0;j<4;j++) acc[f8][j] *= mb[j];
    }
    #pragma unroll
    for (int h=0;h<4;h++){
      f32x4 a0 = acc[h*2+0], a1 = acc[h*2+1];
      uint4 st4;
      st4.x = bpack(a0[0], a0[1]);
      st4.y = bpack(a0[2], a0[3]);
      st4.z = bpack(a1[0], a1[1]);
      st4.w = bpack(a1[2], a1[3]);
      *(uint4*)((char*)vbuf + ((size_t)(bq*4+h)*24 + tau)*1024 + lane*16) = st4;
    }
  }
}

// ---------------- K3: attention v20 = v19 + native exp2/rcp ----------------
// Counter-driven: v19 VALU-issue ~5500 cyc/wave/tile vs ~1200 estimated from
// source ops -> libm-guarded exp2f (~6-10 VALU each, 192/tile-pair) and guarded
// fp32 divides (~10 VALU each, 9/tile) dominate. Replace with bare v_exp_f32 /
// v_rcp_f32 (args in safe range; <=1ulp error << bf16 budget; rcpf already
// validated in r14/r15 runs).
#define L20_SCR  49152            // 4 waves x 2 KiB scratch (1 KiB per tile slot)
#define L20_MASK 57344            // fp32 0/1 [384]
#define L20_TOT  58880

__global__ __attribute__((amdgpu_flat_work_group_size(256,256), amdgpu_waves_per_eu(2,4)))
void attn_kernel20(
    const bf16* __restrict__ xg, const int* __restrict__ mask,
    const float* __restrict__ nb, const bf16* __restrict__ qkvg,
    bf16* __restrict__ kbuf, const bf16* __restrict__ vbuf,
    const float* __restrict__ gb)
{
  __shared__ char sm[L20_TOT];
  const int tid = threadIdx.x;
  const int lane = tid & 63, w = tid >> 6;
  const int g = (lane >> 4)&3, l15 = lane & 15;
  const f32x4 Z = {0.f,0.f,0.f,0.f};

  // h-major: concurrent blocks share one nb[h] plane (L2-resident)
  const u32 bid = blockIdx.x;
  const int h = bid / 384;
  const int b = bid - h*384;

  const char* kbh = (const char*)kbuf + ((size_t)b*4 + h)*24576;
  const char* vbh = (const char*)vbuf + ((size_t)b*4 + h)*24576;

  // ---- stage K (24KiB) + V (24KiB) + mask 0/1 fp32 (1.5KiB) ----
  #pragma unroll
  for (int i=0;i<6;i++){
    unsigned u = (i*4 + w)*1024;
    async_copy16(sm + u,         kbh + u + lane*16);
    async_copy16(sm + 24576 + u, vbh + u + lane*16);
  }
  for (int k = tid; k < NN; k += 256)
    *(float*)(sm + L20_MASK + k*4) = (mask[b*NN + k] != 0) ? 1.f : 0.f;
  __syncthreads();   // vmcnt+lgkm drain; all staging visible

  const unsigned scbA = L20_SCR + w*2048;
  const unsigned scbB = scbA + 1024;
  const float* nbh = nb + (size_t)h*(NN*NN);

  for (int i=0;i<3;i++){
    const int qtA = w*6 + i*2, qtB = qtA + 1;
    const int qbA = qtA*16,    qbB = qtB*16;

    // x A-frags for both q-tiles
    bf16x8 a4A[4], a4B[4];
    #pragma unroll
    for (int t=0;t<4;t++){
      a4A[t] = *(const bf16x8*)(xg + (size_t)(b*NN + qbA + l15)*CC + t*32 + g*8);
      a4B[t] = *(const bf16x8*)(xg + (size_t)(b*NN + qbB + l15)*CC + t*32 + g*8);
    }

    // ---- Q projections (weight frags shared) ----
    f32x4 qA0=Z, qA1=Z, qB0=Z, qB1=Z;
    #pragma unroll
    for (int t=0;t<4;t++){
      bf16x8 bq0 = *(const bf16x8*)(qkvg + (((0*4+h)*4+t)*2+0)*512 + lane*8);
      bf16x8 bq1 = *(const bf16x8*)(qkvg + (((0*4+h)*4+t)*2+1)*512 + lane*8);
      qA0 = MFMA16(a4A[t], bq0, qA0);
      qA1 = MFMA16(a4A[t], bq1, qA1);
      qB0 = MFMA16(a4B[t], bq0, qB0);
      qB1 = MFMA16(a4B[t], bq1, qB1);
    }
    // bounce both Q accums -> B-frags (separate slots; independent lgkm chains)
    #pragma unroll
    for (int f=0;f<2;f++){
      f32x4 qqA = f ? qA1 : qA0, qqB = f ? qB1 : qB0;
      #pragma unroll
      for (int j=0;j<4;j++){
        unsigned r = g*4 + j, cb = (f*16 + l15)*2;
        unsigned off = (r*64 + cb) ^ (((r>>1)&7)<<4);
        *(bf16*)(sm + scbA + off) = (bf16)qqA[j];
        *(bf16*)(sm + scbB + off) = (bf16)qqB[j];
      }
    }
    unsigned aqoff = (l15*64 + g*16) ^ (((l15>>1)&7)<<4);
    bf16x8 aqA = *(const bf16x8*)(sm + scbA + aqoff);
    bf16x8 aqB = *(const bf16x8*)(sm + scbB + aqoff);

    // ---- dual fixed-max softmax (no mask add) + register PV, six 64-key chunks ----
    float sumA = 0.f, sumB = 0.f;
    f32x4 oA0=Z, oA1=Z, oB0=Z, oB1=Z;
    const float* nbqA = nbh + (size_t)(qbA + l15)*NN;
    const float* nbqB = nbh + (size_t)(qbB + l15)*NN;

    #pragma unroll
    for (int c=0;c<6;c++){
      f32x4 stA[4], stB[4];
      #pragma unroll
      for (int nf=0;nf<4;nf++){
        bf16x8 ka = *(const bf16x8*)(sm + (c*4+nf)*1024 + lane*16);   // shared
        float4 nbvA = *(const float4*)(nbqA + c*64 + nf*16 + g*4);
        float4 nbvB = *(const float4*)(nbqB + c*64 + nf*16 + g*4);
        stA[nf] = MFMA16(ka, aqA, __builtin_bit_cast(f32x4, nbvA));
        stB[nf] = MFMA16(ka, aqB, __builtin_bit_cast(f32x4, nbvB));
      }
      #pragma unroll
      for (int nf=0;nf<4;nf++){
        float4 mkf = *(const float4*)(sm + L20_MASK + (c*64 + nf*16 + g*4)*4);  // shared 0/1
        const float* mk = &mkf.x;
        #pragma unroll
        for (int j=0;j<4;j++){
          float pvA = FEXP2(stA[nf][j] - 28.8539008178f);   // == exp(S - 20), no mask term
          float pvB = FEXP2(stB[nf][j] - 28.8539008178f);
          stA[nf][j] = pvA; sumA += pvA*mk[j];              // masked keys excluded via fmac
          stB[nf][j] = pvB; sumB += pvB*mk[j];
        }
      }
      #pragma unroll
      for (int nf=0;nf<4;nf++){
        bf16x8 vv = *(const bf16x8*)(sm + 24576 + (c*4+nf)*1024 + lane*16);   // shared (masked rows = 0)
        bf16x4v vlo = {vv[0],vv[1],vv[2],vv[3]};
        bf16x4v vhi = {vv[4],vv[5],vv[6],vv[7]};
        pvab_t paA = mk_pvab(bpack(stA[nf][0], stA[nf][1]), bpack(stA[nf][2], stA[nf][3]));
        pvab_t paB = mk_pvab(bpack(stB[nf][0], stB[nf][1]), bpack(stB[nf][2], stB[nf][3]));
        oA0 = PVMFMA(paA, vlo, oA0);
        oB0 = PVMFMA(paB, vlo, oB0);
        oA1 = PVMFMA(paA, vhi, oA1);
        oB1 = PVMFMA(paB, vhi, oB1);
      }
    } // c

    // deferred cross-lane sum reduces + broadcast to C/D rows
    sumA += __shfl_xor(sumA, 16); sumA += __shfl_xor(sumA, 32);
    sumB += __shfl_xor(sumB, 16); sumB += __shfl_xor(sumB, 32);
    float rslA = FRCP(sumA), rslB = FRCP(sumB);
    float rcdA[4], rcdB[4];
    #pragma unroll
    for (int j=0;j<4;j++){
      int src = (lane & 0x30) + g*4 + j;
      rcdA[j] = __shfl(rslA, src);
      rcdB[j] = __shfl(rslB, src);
    }

    // ---- gate projections (weight frags shared) ----
    f32x4 gA0=Z, gA1=Z, gB0=Z, gB1=Z;
    #pragma unroll
    for (int t=0;t<4;t++){
      bf16x8 bg0 = *(const bf16x8*)(qkvg + (((3*4+h)*4+t)*2+0)*512 + lane*8);
      bf16x8 bg1 = *(const bf16x8*)(qkvg + (((3*4+h)*4+t)*2+1)*512 + lane*8);
      gA0 = MFMA16(a4A[t], bg0, gA0);
      gA1 = MFMA16(a4A[t], bg1, gA1);
      gB0 = MFMA16(a4B[t], bg0, gB0);
      gB1 = MFMA16(a4B[t], bg1, gB1);
    }

    // ---- wg = (O/s)*sigmoid; bounce to A-frag per slot; store both wavg ----
    #pragma unroll
    for (int f=0;f<2;f++){
      f32x4 ovA = f ? oA1 : oA0, gvA = f ? gA1 : gA0;
      f32x4 ovB = f ? oB1 : oB0, gvB = f ? gB1 : gB0;
      int d = f*16 + l15;
      float gbv = gb[h*32 + d]*LOG2E;
      #pragma unroll
      for (int j=0;j<4;j++){
        unsigned r = g*4 + j, cb2 = (unsigned)d*2;
        unsigned off = (r*64 + cb2) ^ (((r>>1)&7)<<4);
        float gtA = FRCP(1.f + FEXP2(-(gvA[j] + gbv)));
        float gtB = FRCP(1.f + FEXP2(-(gvB[j] + gbv)));
        *(bf16*)(sm + scbA + off) = (bf16)(ovA[j]*rcdA[j]*gtA);
        *(bf16*)(sm + scbB + off) = (bf16)(ovB[j]*rcdB[j]*gtB);
      }
    }
    bf16x8 awgA = *(const bf16x8*)(sm + scbA + aqoff);
    bf16x8 awgB = *(const bf16x8*)(sm + scbB + aqoff);
    *(bf16x8*)((char*)kbuf + ((size_t)b*4 + h)*24576 + qtA*1024 + lane*16) = awgA;
    *(bf16x8*)((char*)kbuf + ((size_t)b*4 + h)*24576 + qtB*1024 + lane*16) = awgB;
  } // i (q-tile pairs)
}

// ---------------- K4: out-projection GEMM: out = wavg · o_w + ob ----------------
__global__ __launch_bounds__(256) void outproj_kernel(
    const bf16* __restrict__ wavg, const bf16* __restrict__ opk,
    const float* __restrict__ ob, float* __restrict__ out)
{
  const int w = threadIdx.x>>6, lane = threadIdx.x&63;
  const int g = (lane>>4)&3, l15 = lane&15;
  const f32x4 Z = {0.f,0.f,0.f,0.f};
  const int W = blockIdx.x*4 + w;
  const int b = W/24, qt = W%24, qb = qt*16;

  bf16x8 aw[4];
  #pragma unroll
  for (int h=0;h<4;h++)
    aw[h] = *(const bf16x8*)((const char*)wavg + ((size_t)b*4 + h)*24576 + qt*1024 + lane*16);

  f32x4 outa[8];
  #pragma unroll
  for (int nf=0;nf<8;nf++) outa[nf] = Z;
  #pragma unroll
  for (int h=0;h<4;h++){
    #pragma unroll
    for (int nf=0;nf<8;nf++){
      bf16x8 bo = *(const bf16x8*)(opk + ((h*8+nf)*64 + lane)*8);
      outa[nf] = MFMA16(aw[h], bo, outa[nf]);
    }
  }
  #pragma unroll
  for (int nf=0;nf<8;nf++){
    int c = nf*16 + l15;
    float obv = ob[c];
    #pragma unroll
    for (int j=0;j<4;j++){
      int qi = qb + g*4 + j;
      out[((size_t)b*NN + qi)*CC + c] = outa[nf][j] + obv;
    }
  }
}

extern "C" void kernel_launch(void* const* d_in, const int* in_sizes, int n_in,
                              void* d_out, int out_size, void* d_ws, size_t ws_size,
                              hipStream_t stream)
{
  (void)in_sizes; (void)n_in; (void)out_size; (void)ws_size;
  const float* pa  = (const float*)d_in[0];
  const int*   msk = (const int*)d_in[1];
  const float* lns = (const float*)d_in[2];
  const float* lnb = (const float*)d_in[3];
  const float* fw  = (const float*)d_in[4];
  const float* qw  = (const float*)d_in[5];
  const float* kw  = (const float*)d_in[6];
  const float* vw  = (const float*)d_in[7];
  const float* gw  = (const float*)d_in[8];
  const float* gbv = (const float*)d_in[9];
  const float* ow  = (const float*)d_in[10];
  const float* ob  = (const float*)d_in[11];
  float* out = (float*)d_out;

  char* ws = (char*)d_ws;
  bf16*  xbuf  = (bf16*)(ws);
  float* nbbuf = (float*)(ws + WS_NB);
  bf16*  qkvg  = (bf16*)(ws + WS_QKVG);
  bf16*  opk   = (bf16*)(ws + WS_OP);
  bf16*  kbuf  = (bf16*)(ws + WS_KB);
  bf16*  vbuf  = (bf16*)(ws + WS_VB);

  pack_kernel<<<40, 256, 0, stream>>>(qw, kw, vw, gw, ow, qkvg, opk);
  ln_kernel<<<1152, 256, 0, stream>>>(pa, lns, lnb, fw, xbuf, nbbuf);
  proj_kv_kernel<<<4608, 256, 0, stream>>>(xbuf, qkvg, msk, kbuf, vbuf);
  attn_kernel20<<<1536, 256, 0, stream>>>(xbuf, msk, nbbuf, qkvg, kbuf, vbuf, gbv);
  outproj_kernel<<<2304, 256, 0, stream>>>(kbuf, opk, ob, out);
}